// Round 6
// baseline (762.591 us; speedup 1.0000x reference)
//
#include <hip/hip_runtime.h>
#include <math.h>

#define MAXNB 1024    // max buckets (N <= 262144 with 256 nodes/bucket)
#define BCH_CNT 2048  // edges per block in count kernel
#define BCH_BIN 2048  // edges per block in bin kernel
#define BCAP  16384   // per-bucket edge capacity in finalize (mean 4096)

typedef __attribute__((ext_vector_type(8))) __bf16 bf16x8;
typedef __attribute__((ext_vector_type(4))) float floatx4;

__device__ inline bf16x8 asbf(uint4 u) {
  union { uint4 u; bf16x8 b; } c; c.u = u; return c.b;
}

// ---------- bf16 helpers ----------
__device__ inline unsigned short f2bf(float f) {
  union { float f; unsigned u; } v; v.f = f;
  unsigned r = v.u + 0x7fffu + ((v.u >> 16) & 1u);   // round-to-nearest-even
  return (unsigned short)(r >> 16);
}
__device__ inline float bf2f(unsigned short u) {
  union { unsigned u; float f; } v; v.u = ((unsigned)u) << 16;
  return v.f;
}
__device__ inline float2 bfp2f2(unsigned u) {       // packed bf16x2 -> float2
  union { unsigned u; float f; } a, b;
  a.u = u << 16;
  b.u = u & 0xffff0000u;
  float2 r; r.x = a.f; r.y = b.f; return r;
}
// split v into hi=bf16(v), lo=bf16(v-hi); packed pair for 2 values
__device__ inline void hilo2(float v0, float v1, unsigned& h, unsigned& l) {
  unsigned short h0 = f2bf(v0); float r0 = v0 - bf2f(h0);
  unsigned short h1 = f2bf(v1); float r1 = v1 - bf2f(h1);
  h = (unsigned)h0 | ((unsigned)h1 << 16);
  l = (unsigned)f2bf(r0) | ((unsigned)f2bf(r1) << 16);
}

// ---------------- CSR build: bucketed two-pass sort ----------------
// B1: dst-bucket histogram only (high occupancy; no random atomics)
__global__ __launch_bounds__(256) void bucket_count_kernel(
    const int* __restrict__ dst, int* __restrict__ bcnt, int E, int NB) {
  __shared__ int hist[MAXNB];
  int tid = threadIdx.x;
  for (int i = tid; i < MAXNB; i += 256) hist[i] = 0;
  __syncthreads();
  int e0 = blockIdx.x * BCH_CNT;
  #pragma unroll
  for (int k = 0; k < BCH_CNT/256; ++k) {
    int e = e0 + k*256 + tid;
    if (e < E) atomicAdd(&hist[dst[e] >> 8], 1);
  }
  __syncthreads();
  for (int i = tid; i < NB; i += 256)
    if (hist[i]) atomicAdd(&bcnt[i], hist[i]);
}

__global__ __launch_bounds__(256) void bucket_scan_kernel(
    const int* __restrict__ bcnt, int* __restrict__ bbase, int* __restrict__ bcur,
    int* __restrict__ rp, int NB, int N, int E) {
  __shared__ int sh[256];
  int t = threadIdx.x;
  int base = t * 4;
  int v0 = (base+0 < NB) ? bcnt[base+0] : 0;
  int v1 = (base+1 < NB) ? bcnt[base+1] : 0;
  int v2 = (base+2 < NB) ? bcnt[base+2] : 0;
  int v3 = (base+3 < NB) ? bcnt[base+3] : 0;
  int s = v0+v1+v2+v3;
  sh[t] = s;
  __syncthreads();
  for (int off=1; off<256; off<<=1){
    int x = (t >= off) ? sh[t-off] : 0;
    __syncthreads();
    sh[t] += x;
    __syncthreads();
  }
  int run = sh[t] - s;
  if (base+0 <= NB) { bbase[base+0] = run; if (base+0 < NB) bcur[base+0] = run; } run += v0;
  if (base+1 <= NB) { bbase[base+1] = run; if (base+1 < NB) bcur[base+1] = run; } run += v1;
  if (base+2 <= NB) { bbase[base+2] = run; if (base+2 < NB) bcur[base+2] = run; } run += v2;
  if (base+3 <= NB) { bbase[base+3] = run; if (base+3 < NB) bcur[base+3] = run; }
  if (t == 0) rp[N] = E;
}

// B3: bin edges into bucket-grouped ebuf; also does the cnt_out (out-degree)
// random atomics — their latency hides behind the LDS staging work.
__global__ __launch_bounds__(256) void bin_kernel(
    const int* __restrict__ src, const int* __restrict__ dst,
    int* __restrict__ bcur, int* __restrict__ cnt_out,
    uint2* __restrict__ ebuf, int E, int NB) {
  __shared__ int hist[MAXNB];
  __shared__ int scanb[MAXNB];
  __shared__ int rbase[MAXNB];
  __shared__ int lcur[MAXNB];
  __shared__ int tmp[256];
  __shared__ uint2 stage[BCH_BIN];
  int tid = threadIdx.x;
  int e0 = blockIdx.x * BCH_BIN;
  int nedge = E - e0; if (nedge > BCH_BIN) nedge = BCH_BIN; if (nedge < 0) nedge = 0;
  for (int i = tid; i < MAXNB; i += 256) hist[i] = 0;
  __syncthreads();
  #pragma unroll
  for (int k = 0; k < BCH_BIN/256; ++k) {
    int e = e0 + k*256 + tid;
    if (e < E) atomicAdd(&hist[dst[e] >> 8], 1);
  }
  __syncthreads();
  {
    int base = tid * 4;
    int v0 = hist[base+0], v1 = hist[base+1], v2 = hist[base+2], v3 = hist[base+3];
    int s = v0+v1+v2+v3;
    tmp[tid] = s;
    __syncthreads();
    for (int off=1; off<256; off<<=1){
      int x = (tid >= off) ? tmp[tid-off] : 0;
      __syncthreads();
      tmp[tid] += x;
      __syncthreads();
    }
    int run = tmp[tid] - s;
    scanb[base+0] = run; run += v0;
    scanb[base+1] = run; run += v1;
    scanb[base+2] = run; run += v2;
    scanb[base+3] = run;
  }
  __syncthreads();
  for (int i = tid; i < NB; i += 256) {
    int h = hist[i];
    rbase[i] = h ? atomicAdd(&bcur[i], h) : 0;
    lcur[i] = scanb[i];
  }
  __syncthreads();
  #pragma unroll
  for (int k = 0; k < BCH_BIN/256; ++k) {
    int e = e0 + k*256 + tid;
    if (e < E) {
      int s = src[e];
      int d = dst[e];
      atomicAdd(&cnt_out[s], 1);        // out-degree (latency hidden by staging)
      int b = d >> 8;
      int p = atomicAdd(&lcur[b], 1);
      stage[p] = make_uint2((unsigned)s, (unsigned)d);
    }
  }
  __syncthreads();
  for (int i = tid; i < nedge; i += 256) {
    uint2 ed = stage[i];
    int b = (int)(ed.y >> 8);
    ebuf[rbase[b] + (i - scanb[b])] = ed;
  }
}

__global__ __launch_bounds__(256) void finalize_kernel(
    const uint2* __restrict__ ebuf, const int* __restrict__ bbase,
    int* __restrict__ rp, float* __restrict__ din_is,
    int* __restrict__ col, int N) {
  __shared__ int lcnt[256];
  __shared__ int lrp[257];
  __shared__ int lcur[256];
  __shared__ int tmp[256];
  __shared__ int colbuf[BCAP];
  int b = blockIdx.x;
  int tid = threadIdx.x;
  int node0 = b << 8;
  int e0 = bbase[b], e1 = bbase[b+1];
  int ne = e1 - e0;
  lcnt[tid] = 0;
  __syncthreads();
  for (int i = tid; i < ne; i += 256)
    atomicAdd(&lcnt[ebuf[e0+i].y & 255], 1);
  __syncthreads();
  int c = lcnt[tid];
  tmp[tid] = c;
  __syncthreads();
  for (int off=1; off<256; off<<=1){
    int x = (tid >= off) ? tmp[tid-off] : 0;
    __syncthreads();
    tmp[tid] += x;
    __syncthreads();
  }
  lrp[tid] = tmp[tid] - c;
  lcur[tid] = tmp[tid] - c;
  if (tid == 255) lrp[256] = tmp[255];
  __syncthreads();
  int node = node0 + tid;
  if (node < N) {
    rp[node] = e0 + lrp[tid];
    int cc = c < 1 ? 1 : c;
    din_is[node] = rsqrtf((float)cc);
  }
  if (ne <= BCAP) {
    for (int i = tid; i < ne; i += 256) {
      uint2 ed = ebuf[e0+i];
      int p = atomicAdd(&lcur[ed.y & 255], 1);
      colbuf[p] = (int)ed.x;
    }
    __syncthreads();
    for (int i = tid; i < ne; i += 256) col[e0+i] = colbuf[i];
  } else {
    for (int i = tid; i < ne; i += 256) {
      uint2 ed = ebuf[e0+i];
      int p = atomicAdd(&lcur[ed.y & 255], 1);
      col[e0+p] = (int)ed.x;
    }
  }
}

__global__ void invsqrt_dout_kernel(const int* __restrict__ cout,
                                    float* __restrict__ dout_is, int N) {
  int i = blockIdx.x * blockDim.x + threadIdx.x;
  if (i < N) {
    int b = cout[i]; if (b < 1) b = 1;
    dout_is[i] = rsqrtf((float)b);
  }
}

// ---------------- W -> transposed bf16 hi/lo: Wt[n][k], padded to npad rows ----------------
__global__ void wt_hilo_kernel(const float* __restrict__ W, unsigned short* __restrict__ Wthi,
                               unsigned short* __restrict__ Wtlo, int nreal, int npad) {
  int idx = blockIdx.x * blockDim.x + threadIdx.x;
  if (idx >= npad * 128) return;
  int n = idx >> 7;
  int k = idx & 127;
  float v = (n < nreal) ? W[k * nreal + n] : 0.f;
  unsigned short h = f2bf(v);
  float r = v - bf2f(h);
  Wthi[idx] = h;
  Wtlo[idx] = f2bf(r);
}

// ---------------- cast x (fp32 row) -> bf16 row pre-scaled by dout_is ----------------
__global__ void cast_scale_kernel(const float* __restrict__ x, const float* __restrict__ dout_is,
                                  unsigned* __restrict__ xb2, int n4) {
  int i = blockIdx.x * blockDim.x + threadIdx.x;
  if (i >= n4) return;
  float4 v = ((const float4*)x)[i];
  int row = i >> 5;
  float sc = dout_is[row];
  unsigned lo = (unsigned)f2bf(v.x * sc) | ((unsigned)f2bf(v.y * sc) << 16);
  unsigned hi = (unsigned)f2bf(v.z * sc) | ((unsigned)f2bf(v.w * sc) << 16);
  ((uint2*)xb2)[i] = make_uint2(lo, hi);
}

// ---------------- aggregation over bf16 rows, D=128, hi/lo bf16 output ----------------
__device__ inline void acc8(float* a, uint4 v) {
  float2 f;
  f = bfp2f2(v.x); a[0]+=f.x; a[1]+=f.y;
  f = bfp2f2(v.y); a[2]+=f.x; a[3]+=f.y;
  f = bfp2f2(v.z); a[4]+=f.x; a[5]+=f.y;
  f = bfp2f2(v.w); a[6]+=f.x; a[7]+=f.y;
}

__global__ __launch_bounds__(256) void agg128_bf16_kernel(
    const uint4* __restrict__ hb4,
    const int* __restrict__ rp, const int* __restrict__ col,
    const float* __restrict__ din_is,
    uint4* __restrict__ Ahi, uint4* __restrict__ Alo, int N) {
  int wave = (blockIdx.x * blockDim.x + threadIdx.x) >> 6;
  int lane = threadIdx.x & 63;
  int g = lane >> 4, j = lane & 15;
  int d = wave * 4 + g;
  if (d >= N) return;
  int s0 = rp[d], s1 = rp[d+1];
  float a[8] = {0.f,0.f,0.f,0.f,0.f,0.f,0.f,0.f};
  int e = s0;
  for (; e + 4 <= s1; e += 4) {
    int c0 = col[e], c1 = col[e+1], c2 = col[e+2], c3 = col[e+3];
    uint4 v0 = hb4[(size_t)c0*16 + j];
    uint4 v1 = hb4[(size_t)c1*16 + j];
    uint4 v2 = hb4[(size_t)c2*16 + j];
    uint4 v3 = hb4[(size_t)c3*16 + j];
    acc8(a, v0); acc8(a, v1); acc8(a, v2); acc8(a, v3);
  }
  for (; e < s1; ++e) {
    uint4 v = hb4[(size_t)col[e]*16 + j];
    acc8(a, v);
  }
  float di = din_is[d];
  uint4 H, L;
  hilo2(a[0]*di, a[1]*di, H.x, L.x);
  hilo2(a[2]*di, a[3]*di, H.y, L.y);
  hilo2(a[4]*di, a[5]*di, H.z, L.z);
  hilo2(a[6]*di, a[7]*di, H.w, L.w);
  Ahi[(size_t)d*16 + j] = H;
  Alo[(size_t)d*16 + j] = L;
}

// ---------------- MFMA GEMM: Out[N,NOUT] = (Ahi+Alo)[N,128] @ Wt^T, hi/lo 3-product ----------------
template<int NCT, bool BF16OUT>
__global__ __launch_bounds__(256) void gemm_mfma_kernel(
    const uint4* __restrict__ Ahi, const uint4* __restrict__ Alo,
    const uint4* __restrict__ Bhi, const uint4* __restrict__ Blo,
    const float* __restrict__ bias, float* __restrict__ Out,
    unsigned short* __restrict__ OutB, const float* __restrict__ rowscale, int N) {
  int wave = threadIdx.x >> 6;
  int lane = threadIdx.x & 63;
  int quad = lane >> 4, l15 = lane & 15;
  int row0 = blockIdx.x * 64 + wave * 16;
  int row = row0 + l15;
  int rl = row < N ? row : N - 1;
  floatx4 acc[NCT];
  #pragma unroll
  for (int ct = 0; ct < NCT; ++ct) acc[ct] = (floatx4){0.f, 0.f, 0.f, 0.f};
  #pragma unroll
  for (int kc = 0; kc < 4; ++kc) {
    uint4 ah = Ahi[(size_t)rl*16 + kc*4 + quad];
    uint4 al = Alo[(size_t)rl*16 + kc*4 + quad];
    #pragma unroll
    for (int ct = 0; ct < NCT; ++ct) {
      int nr = ct*16 + l15;
      uint4 bh = Bhi[nr*16 + kc*4 + quad];
      uint4 bl = Blo[nr*16 + kc*4 + quad];
      acc[ct] = __builtin_amdgcn_mfma_f32_16x16x32_bf16(asbf(ah), asbf(bh), acc[ct], 0, 0, 0);
      acc[ct] = __builtin_amdgcn_mfma_f32_16x16x32_bf16(asbf(ah), asbf(bl), acc[ct], 0, 0, 0);
      acc[ct] = __builtin_amdgcn_mfma_f32_16x16x32_bf16(asbf(al), asbf(bh), acc[ct], 0, 0, 0);
    }
  }
  if constexpr (BF16OUT) {
    #pragma unroll
    for (int r = 0; r < 4; ++r) {
      int grow = row0 + quad*4 + r;
      if (grow < N) {
        float sc = rowscale[grow];
        #pragma unroll
        for (int ct = 0; ct < NCT; ++ct) {
          int colc = ct*16 + l15;
          if (colc < 40) OutB[(size_t)grow*40 + colc] = f2bf(acc[ct][r] * sc);
        }
      }
    }
  } else {
    #pragma unroll
    for (int ct = 0; ct < NCT; ++ct) {
      int colc = ct*16 + l15;
      float bs = bias[colc];
      #pragma unroll
      for (int r = 0; r < 4; ++r) {
        int grow = row0 + quad*4 + r;
        if (grow < N) Out[(size_t)grow*128 + colc] = acc[ct][r] + bs;
      }
    }
  }
}

// ---------------- BatchNorm ----------------
__global__ void bn_reduce_kernel(const float* __restrict__ h, float* __restrict__ gsum,
                                 float* __restrict__ gsumsq, int N, int rpb) {
  int f = threadIdx.x;
  int r0 = blockIdx.x * rpb;
  int r1 = r0 + rpb; if (r1 > N) r1 = N;
  float s = 0.f, ss = 0.f;
  for (int r = r0; r < r1; ++r) {
    float v = h[(size_t)r*128 + f];
    s += v; ss += v*v;
  }
  atomicAdd(&gsum[f], s);
  atomicAdd(&gsumsq[f], ss);
}

__global__ void bn_params_kernel(const float* __restrict__ gsum, const float* __restrict__ gsumsq,
                                 const float* __restrict__ g, const float* __restrict__ be,
                                 float* __restrict__ colA, float* __restrict__ colB, float invN) {
  int f = threadIdx.x;
  float mu  = gsum[f] * invN;
  float var = gsumsq[f] * invN - mu*mu;
  if (var < 0.f) var = 0.f;
  float rs = rsqrtf(var + 1e-5f);
  float a = g[f] * rs;
  colA[f] = a;
  colB[f] = be[f] - mu*a;
}

__global__ void bn_apply_bf16_kernel(const float* __restrict__ raw, const float* __restrict__ colA,
                                     const float* __restrict__ colB, const float* __restrict__ dout_is,
                                     unsigned* __restrict__ outb, int n4) {
  int i = blockIdx.x * blockDim.x + threadIdx.x;
  if (i >= n4) return;
  float4 v = ((const float4*)raw)[i];
  int c4 = i & 31;
  int row = i >> 5;
  float sc = dout_is[row];
  float4 a = ((const float4*)colA)[c4];
  float4 b = ((const float4*)colB)[c4];
  float x0 = fmaxf(v.x*a.x + b.x, 0.f) * sc;
  float x1 = fmaxf(v.y*a.y + b.y, 0.f) * sc;
  float x2 = fmaxf(v.z*a.z + b.z, 0.f) * sc;
  float x3 = fmaxf(v.w*a.w + b.w, 0.f) * sc;
  unsigned lo = (unsigned)f2bf(x0) | ((unsigned)f2bf(x1) << 16);
  unsigned hi = (unsigned)f2bf(x2) | ((unsigned)f2bf(x3) << 16);
  ((uint2*)outb)[i] = make_uint2(lo, hi);
}

__global__ void bn_apply_hilo_kernel(const float* __restrict__ raw, const float* __restrict__ colA,
                                     const float* __restrict__ colB,
                                     uint4* __restrict__ Ahi, uint4* __restrict__ Alo, int n8) {
  int i = blockIdx.x * blockDim.x + threadIdx.x;
  if (i >= n8) return;
  int j = i & 15;
  float4 v0 = ((const float4*)raw)[2*i];
  float4 v1 = ((const float4*)raw)[2*i+1];
  float4 a0 = ((const float4*)colA)[2*j];
  float4 a1 = ((const float4*)colA)[2*j+1];
  float4 b0 = ((const float4*)colB)[2*j];
  float4 b1 = ((const float4*)colB)[2*j+1];
  float y0 = fmaxf(v0.x*a0.x + b0.x, 0.f);
  float y1 = fmaxf(v0.y*a0.y + b0.y, 0.f);
  float y2 = fmaxf(v0.z*a0.z + b0.z, 0.f);
  float y3 = fmaxf(v0.w*a0.w + b0.w, 0.f);
  float y4 = fmaxf(v1.x*a1.x + b1.x, 0.f);
  float y5 = fmaxf(v1.y*a1.y + b1.y, 0.f);
  float y6 = fmaxf(v1.z*a1.z + b1.z, 0.f);
  float y7 = fmaxf(v1.w*a1.w + b1.w, 0.f);
  uint4 H, L;
  hilo2(y0, y1, H.x, L.x);
  hilo2(y2, y3, H.y, L.y);
  hilo2(y4, y5, H.z, L.z);
  hilo2(y6, y7, H.w, L.w);
  Ahi[i] = H;
  Alo[i] = L;
}

// ---------------- layer 3: aggregate 40-dim bf16 (pre-scaled) + bias + log_softmax ----------------
__global__ __launch_bounds__(256) void final_kernel(
    const unsigned* __restrict__ tb,
    const int* __restrict__ rp, const int* __restrict__ col,
    const float* __restrict__ din_is, const float* __restrict__ b3,
    float* __restrict__ out, int N) {
  int wave = (blockIdx.x * blockDim.x + threadIdx.x) >> 6;
  int g = (threadIdx.x >> 5) & 1;
  int j = threadIdx.x & 31;
  int d = wave * 2 + g;
  if (d >= N) return;
  bool act = (j < 20);
  int s0 = rp[d], s1 = rp[d+1];
  float a0 = 0.f, a1 = 0.f;
  int e = s0;
  for (; e + 4 <= s1; e += 4) {
    int c0 = col[e], c1 = col[e+1], c2 = col[e+2], c3 = col[e+3];
    unsigned u0 = act ? tb[(size_t)c0*20 + j] : 0u;
    unsigned u1 = act ? tb[(size_t)c1*20 + j] : 0u;
    unsigned u2 = act ? tb[(size_t)c2*20 + j] : 0u;
    unsigned u3 = act ? tb[(size_t)c3*20 + j] : 0u;
    float2 f0 = bfp2f2(u0), f1 = bfp2f2(u1), f2 = bfp2f2(u2), f3 = bfp2f2(u3);
    a0 += (f0.x + f1.x) + (f2.x + f3.x);
    a1 += (f0.y + f1.y) + (f2.y + f3.y);
  }
  for (; e < s1; ++e) {
    unsigned u = act ? tb[(size_t)col[e]*20 + j] : 0u;
    float2 f = bfp2f2(u);
    a0 += f.x; a1 += f.y;
  }
  float di = din_is[d];
  float z0 = act ? di*a0 + b3[2*j]   : -1e30f;
  float z1 = act ? di*a1 + b3[2*j+1] : -1e30f;
  float m = fmaxf(z0, z1);
  #pragma unroll
  for (int off=16; off>0; off>>=1) m = fmaxf(m, __shfl_xor(m, off, 32));
  float s = act ? (expf(z0-m) + expf(z1-m)) : 0.f;
  #pragma unroll
  for (int off=16; off>0; off>>=1) s += __shfl_xor(s, off, 32);
  float lg = logf(s);
  if (act) {
    float2 o = make_float2(z0 - m - lg, z1 - m - lg);
    ((float2*)(out + (size_t)d*40))[j] = o;
  }
}

// ---------------- host ----------------
extern "C" void kernel_launch(void* const* d_in, const int* in_sizes, int n_in,
                              void* d_out, int out_size, void* d_ws, size_t ws_size,
                              hipStream_t stream) {
  const float* x   = (const float*)d_in[0];
  const int*   src = (const int*)d_in[1];
  const int*   dst = (const int*)d_in[2];
  const float* W1  = (const float*)d_in[3];
  const float* b1  = (const float*)d_in[4];
  const float* g1  = (const float*)d_in[5];
  const float* be1 = (const float*)d_in[6];
  const float* W2  = (const float*)d_in[7];
  const float* b2  = (const float*)d_in[8];
  const float* g2  = (const float*)d_in[9];
  const float* be2 = (const float*)d_in[10];
  const float* W3  = (const float*)d_in[11];
  const float* b3  = (const float*)d_in[12];
  const int E = in_sizes[1];
  const int D = in_sizes[4];     // 128
  const int N = in_sizes[0] / D; // 100000
  float* out = (float*)d_out;

  char* p = (char*)d_ws;
  auto alloc = [&](size_t bytes) { char* q = p; p += (bytes + 255) & ~(size_t)255; return q; };
  int* rp        = (int*)alloc((size_t)(N+1)*4);
  int* cnt_out   = (int*)alloc((size_t)N*4);
  float* din_is  = (float*)alloc((size_t)N*4);
  float* dout_is = (float*)alloc((size_t)N*4);
  float* gsum    = (float*)alloc((size_t)D*4);
  float* gsumsq  = (float*)alloc((size_t)D*4);
  float* colAp   = (float*)alloc((size_t)D*4);
  float* colBp   = (float*)alloc((size_t)D*4);
  int* bcnt      = (int*)alloc((size_t)MAXNB*4);
  int* bbase     = (int*)alloc((size_t)(MAXNB+1)*4);
  int* bcur      = (int*)alloc((size_t)MAXNB*4);
  unsigned short* Wt1hi = (unsigned short*)alloc(128*128*2);
  unsigned short* Wt1lo = (unsigned short*)alloc(128*128*2);
  unsigned short* Wt2hi = (unsigned short*)alloc(128*128*2);
  unsigned short* Wt2lo = (unsigned short*)alloc(128*128*2);
  unsigned short* Wt3hi = (unsigned short*)alloc(48*128*2);
  unsigned short* Wt3lo = (unsigned short*)alloc(48*128*2);
  int*   col     = (int*)alloc((size_t)E*4);
  float* bufA    = (float*)alloc((size_t)N*D*4);      // fp32 GEMM output
  uint4* Ahi     = (uint4*)alloc((size_t)N*D*2);      // bf16 hi
  uint4* Alo     = (uint4*)alloc((size_t)N*D*2);      // bf16 lo
  unsigned* bf16buf = (unsigned*)alloc((size_t)N*D*2);
  // ebuf aliases bufA: CSR build finishes before bufA's first write
  uint2* ebuf = (uint2*)bufA;

  const int NB = (N + 255) >> 8;
  int nbN = (N + 255)/256;
  int cntB = (E + BCH_CNT - 1)/BCH_CNT;
  int binB = (E + BCH_BIN - 1)/BCH_BIN;

  hipMemsetAsync(cnt_out, 0, (size_t)N*4, stream);
  hipMemsetAsync(bcnt, 0, (size_t)MAXNB*4, stream);
  wt_hilo_kernel<<<(128*128+255)/256, 256, 0, stream>>>(W1, Wt1hi, Wt1lo, 128, 128);
  wt_hilo_kernel<<<(128*128+255)/256, 256, 0, stream>>>(W2, Wt2hi, Wt2lo, 128, 128);
  wt_hilo_kernel<<<(48*128+255)/256, 256, 0, stream>>>(W3, Wt3hi, Wt3lo, 40, 48);
  bucket_count_kernel<<<cntB, 256, 0, stream>>>(dst, bcnt, E, NB);
  bucket_scan_kernel<<<1, 256, 0, stream>>>(bcnt, bbase, bcur, rp, NB, N, E);
  bin_kernel<<<binB, 256, 0, stream>>>(src, dst, bcur, cnt_out, ebuf, E, NB);
  finalize_kernel<<<NB, 256, 0, stream>>>(ebuf, bbase, rp, din_is, col, N);
  invsqrt_dout_kernel<<<nbN, 256, 0, stream>>>(cnt_out, dout_is, N);

  int aggb   = ((N + 3)/4*64 + 255)/256;    // 4 dst per wave
  int finb   = ((N + 1)/2*64 + 255)/256;    // 2 dst per wave
  int gemb   = (N + 63)/64;                 // 64 rows per block
  int rpb  = (N + 511)/512;
  int nel4 = (N*D)/4;
  int nel8 = (N*D)/8;

  // layer 1
  cast_scale_kernel<<<(nel4+255)/256, 256, 0, stream>>>(x, dout_is, bf16buf, nel4);
  agg128_bf16_kernel<<<aggb, 256, 0, stream>>>((const uint4*)bf16buf, rp, col, din_is, Ahi, Alo, N);
  gemm_mfma_kernel<8,false><<<gemb, 256, 0, stream>>>(Ahi, Alo, (const uint4*)Wt1hi, (const uint4*)Wt1lo,
                                                      b1, bufA, nullptr, nullptr, N);
  hipMemsetAsync(gsum, 0, (size_t)D*4, stream);
  hipMemsetAsync(gsumsq, 0, (size_t)D*4, stream);
  bn_reduce_kernel<<<512, 128, 0, stream>>>(bufA, gsum, gsumsq, N, rpb);
  bn_params_kernel<<<1, 128, 0, stream>>>(gsum, gsumsq, g1, be1, colAp, colBp, 1.0f/(float)N);
  bn_apply_bf16_kernel<<<(nel4+255)/256, 256, 0, stream>>>(bufA, colAp, colBp, dout_is, bf16buf, nel4);

  // layer 2
  agg128_bf16_kernel<<<aggb, 256, 0, stream>>>((const uint4*)bf16buf, rp, col, din_is, Ahi, Alo, N);
  gemm_mfma_kernel<8,false><<<gemb, 256, 0, stream>>>(Ahi, Alo, (const uint4*)Wt2hi, (const uint4*)Wt2lo,
                                                      b2, bufA, nullptr, nullptr, N);
  hipMemsetAsync(gsum, 0, (size_t)D*4, stream);
  hipMemsetAsync(gsumsq, 0, (size_t)D*4, stream);
  bn_reduce_kernel<<<512, 128, 0, stream>>>(bufA, gsum, gsumsq, N, rpb);
  bn_params_kernel<<<1, 128, 0, stream>>>(gsum, gsumsq, g2, be2, colAp, colBp, 1.0f/(float)N);
  bn_apply_hilo_kernel<<<(nel8+255)/256, 256, 0, stream>>>(bufA, colAp, colBp, Ahi, Alo, nel8);

  // layer 3: MFMA GEMM to 40 dims (bf16 out pre-scaled by dout), then agg + softmax
  gemm_mfma_kernel<3,true><<<gemb, 256, 0, stream>>>(Ahi, Alo, (const uint4*)Wt3hi, (const uint4*)Wt3lo,
                                                     nullptr, nullptr, (unsigned short*)bf16buf, dout_is, N);
  final_kernel<<<finb, 256, 0, stream>>>((const unsigned*)bf16buf, rp, col, din_is, b3, out, N);
}

// Round 7
// 742.846 us; speedup vs baseline: 1.0266x; 1.0266x over previous
//
#include <hip/hip_runtime.h>
#include <math.h>

#define MAXNB 1024    // max buckets (N <= 262144 with 256 nodes/bucket)
#define BCH_CNT 2048  // edges per block in count kernel
#define BCH_BIN 2048  // edges per block in bin kernel
#define BCAP  16384   // per-bucket edge capacity in finalize (mean 4096)

typedef __attribute__((ext_vector_type(8))) __bf16 bf16x8;
typedef __attribute__((ext_vector_type(4))) float floatx4;

__device__ inline bf16x8 asbf(uint4 u) {
  union { uint4 u; bf16x8 b; } c; c.u = u; return c.b;
}

// ---------- bf16 helpers ----------
__device__ inline unsigned short f2bf(float f) {
  union { float f; unsigned u; } v; v.f = f;
  unsigned r = v.u + 0x7fffu + ((v.u >> 16) & 1u);   // round-to-nearest-even
  return (unsigned short)(r >> 16);
}
__device__ inline float bf2f(unsigned short u) {
  union { unsigned u; float f; } v; v.u = ((unsigned)u) << 16;
  return v.f;
}
__device__ inline float2 bfp2f2(unsigned u) {       // packed bf16x2 -> float2
  union { unsigned u; float f; } a, b;
  a.u = u << 16;
  b.u = u & 0xffff0000u;
  float2 r; r.x = a.f; r.y = b.f; return r;
}
// split v into hi=bf16(v), lo=bf16(v-hi); packed pair for 2 values
__device__ inline void hilo2(float v0, float v1, unsigned& h, unsigned& l) {
  unsigned short h0 = f2bf(v0); float r0 = v0 - bf2f(h0);
  unsigned short h1 = f2bf(v1); float r1 = v1 - bf2f(h1);
  h = (unsigned)h0 | ((unsigned)h1 << 16);
  l = (unsigned)f2bf(r0) | ((unsigned)f2bf(r1) << 16);
}

// ---------------- CSR build: bucketed two-pass sort ----------------
// B1: dst-bucket histogram + out-degree random atomics (max occupancy: 4KB LDS,
// 782 blocks — the random atomics need TLP, nothing else in flight here)
__global__ __launch_bounds__(256) void bucket_count_kernel(
    const int* __restrict__ src, const int* __restrict__ dst,
    int* __restrict__ bcnt, int* __restrict__ cnt_out, int E, int NB) {
  __shared__ int hist[MAXNB];
  int tid = threadIdx.x;
  for (int i = tid; i < MAXNB; i += 256) hist[i] = 0;
  __syncthreads();
  int e0 = blockIdx.x * BCH_CNT;
  #pragma unroll
  for (int k = 0; k < BCH_CNT/256; ++k) {
    int e = e0 + k*256 + tid;
    if (e < E) {
      atomicAdd(&hist[dst[e] >> 8], 1);
      atomicAdd(&cnt_out[src[e]], 1);
    }
  }
  __syncthreads();
  for (int i = tid; i < NB; i += 256)
    if (hist[i]) atomicAdd(&bcnt[i], hist[i]);
}

__global__ __launch_bounds__(256) void bucket_scan_kernel(
    const int* __restrict__ bcnt, int* __restrict__ bbase, int* __restrict__ bcur,
    int* __restrict__ rp, int NB, int N, int E) {
  __shared__ int sh[256];
  int t = threadIdx.x;
  int base = t * 4;
  int v0 = (base+0 < NB) ? bcnt[base+0] : 0;
  int v1 = (base+1 < NB) ? bcnt[base+1] : 0;
  int v2 = (base+2 < NB) ? bcnt[base+2] : 0;
  int v3 = (base+3 < NB) ? bcnt[base+3] : 0;
  int s = v0+v1+v2+v3;
  sh[t] = s;
  __syncthreads();
  for (int off=1; off<256; off<<=1){
    int x = (t >= off) ? sh[t-off] : 0;
    __syncthreads();
    sh[t] += x;
    __syncthreads();
  }
  int run = sh[t] - s;
  if (base+0 <= NB) { bbase[base+0] = run; if (base+0 < NB) bcur[base+0] = run; } run += v0;
  if (base+1 <= NB) { bbase[base+1] = run; if (base+1 < NB) bcur[base+1] = run; } run += v1;
  if (base+2 <= NB) { bbase[base+2] = run; if (base+2 < NB) bcur[base+2] = run; } run += v2;
  if (base+3 <= NB) { bbase[base+3] = run; if (base+3 < NB) bcur[base+3] = run; }
  if (t == 0) rp[N] = E;
}

// B3: bin edges into bucket-grouped ebuf via LDS staging (no random atomics)
__global__ __launch_bounds__(256) void bin_kernel(
    const int* __restrict__ src, const int* __restrict__ dst,
    int* __restrict__ bcur, uint2* __restrict__ ebuf, int E, int NB) {
  __shared__ int hist[MAXNB];
  __shared__ int scanb[MAXNB];
  __shared__ int rbase[MAXNB];
  __shared__ int lcur[MAXNB];
  __shared__ int tmp[256];
  __shared__ uint2 stage[BCH_BIN];
  int tid = threadIdx.x;
  int e0 = blockIdx.x * BCH_BIN;
  int nedge = E - e0; if (nedge > BCH_BIN) nedge = BCH_BIN; if (nedge < 0) nedge = 0;
  for (int i = tid; i < MAXNB; i += 256) hist[i] = 0;
  __syncthreads();
  #pragma unroll
  for (int k = 0; k < BCH_BIN/256; ++k) {
    int e = e0 + k*256 + tid;
    if (e < E) atomicAdd(&hist[dst[e] >> 8], 1);
  }
  __syncthreads();
  {
    int base = tid * 4;
    int v0 = hist[base+0], v1 = hist[base+1], v2 = hist[base+2], v3 = hist[base+3];
    int s = v0+v1+v2+v3;
    tmp[tid] = s;
    __syncthreads();
    for (int off=1; off<256; off<<=1){
      int x = (tid >= off) ? tmp[tid-off] : 0;
      __syncthreads();
      tmp[tid] += x;
      __syncthreads();
    }
    int run = tmp[tid] - s;
    scanb[base+0] = run; run += v0;
    scanb[base+1] = run; run += v1;
    scanb[base+2] = run; run += v2;
    scanb[base+3] = run;
  }
  __syncthreads();
  for (int i = tid; i < NB; i += 256) {
    int h = hist[i];
    rbase[i] = h ? atomicAdd(&bcur[i], h) : 0;
    lcur[i] = scanb[i];
  }
  __syncthreads();
  #pragma unroll
  for (int k = 0; k < BCH_BIN/256; ++k) {
    int e = e0 + k*256 + tid;
    if (e < E) {
      int d = dst[e];
      int b = d >> 8;
      int p = atomicAdd(&lcur[b], 1);
      stage[p] = make_uint2((unsigned)src[e], (unsigned)d);
    }
  }
  __syncthreads();
  for (int i = tid; i < nedge; i += 256) {
    uint2 ed = stage[i];
    int b = (int)(ed.y >> 8);
    ebuf[rbase[b] + (i - scanb[b])] = ed;
  }
}

__global__ __launch_bounds__(256) void finalize_kernel(
    const uint2* __restrict__ ebuf, const int* __restrict__ bbase,
    int* __restrict__ rp, float* __restrict__ din_is,
    int* __restrict__ col, int N) {
  __shared__ int lcnt[256];
  __shared__ int lrp[257];
  __shared__ int lcur[256];
  __shared__ int tmp[256];
  __shared__ int colbuf[BCAP];
  int b = blockIdx.x;
  int tid = threadIdx.x;
  int node0 = b << 8;
  int e0 = bbase[b], e1 = bbase[b+1];
  int ne = e1 - e0;
  lcnt[tid] = 0;
  __syncthreads();
  for (int i = tid; i < ne; i += 256)
    atomicAdd(&lcnt[ebuf[e0+i].y & 255], 1);
  __syncthreads();
  int c = lcnt[tid];
  tmp[tid] = c;
  __syncthreads();
  for (int off=1; off<256; off<<=1){
    int x = (tid >= off) ? tmp[tid-off] : 0;
    __syncthreads();
    tmp[tid] += x;
    __syncthreads();
  }
  lrp[tid] = tmp[tid] - c;
  lcur[tid] = tmp[tid] - c;
  if (tid == 255) lrp[256] = tmp[255];
  __syncthreads();
  int node = node0 + tid;
  if (node < N) {
    rp[node] = e0 + lrp[tid];
    int cc = c < 1 ? 1 : c;
    din_is[node] = rsqrtf((float)cc);
  }
  if (ne <= BCAP) {
    for (int i = tid; i < ne; i += 256) {
      uint2 ed = ebuf[e0+i];
      int p = atomicAdd(&lcur[ed.y & 255], 1);
      colbuf[p] = (int)ed.x;
    }
    __syncthreads();
    for (int i = tid; i < ne; i += 256) col[e0+i] = colbuf[i];
  } else {
    for (int i = tid; i < ne; i += 256) {
      uint2 ed = ebuf[e0+i];
      int p = atomicAdd(&lcur[ed.y & 255], 1);
      col[e0+p] = (int)ed.x;
    }
  }
}

__global__ void invsqrt_dout_kernel(const int* __restrict__ cout,
                                    float* __restrict__ dout_is, int N) {
  int i = blockIdx.x * blockDim.x + threadIdx.x;
  if (i < N) {
    int b = cout[i]; if (b < 1) b = 1;
    dout_is[i] = rsqrtf((float)b);
  }
}

// ---------------- W -> transposed bf16 hi/lo: Wt[n][k], padded to npad rows ----------------
__global__ void wt_hilo_kernel(const float* __restrict__ W, unsigned short* __restrict__ Wthi,
                               unsigned short* __restrict__ Wtlo, int nreal, int npad) {
  int idx = blockIdx.x * blockDim.x + threadIdx.x;
  if (idx >= npad * 128) return;
  int n = idx >> 7;
  int k = idx & 127;
  float v = (n < nreal) ? W[k * nreal + n] : 0.f;
  unsigned short h = f2bf(v);
  float r = v - bf2f(h);
  Wthi[idx] = h;
  Wtlo[idx] = f2bf(r);
}

// ---------------- cast x (fp32 row) -> bf16 row pre-scaled by dout_is ----------------
__global__ void cast_scale_kernel(const float* __restrict__ x, const float* __restrict__ dout_is,
                                  unsigned* __restrict__ xb2, int n4) {
  int i = blockIdx.x * blockDim.x + threadIdx.x;
  if (i >= n4) return;
  float4 v = ((const float4*)x)[i];
  int row = i >> 5;
  float sc = dout_is[row];
  unsigned lo = (unsigned)f2bf(v.x * sc) | ((unsigned)f2bf(v.y * sc) << 16);
  unsigned hi = (unsigned)f2bf(v.z * sc) | ((unsigned)f2bf(v.w * sc) << 16);
  ((uint2*)xb2)[i] = make_uint2(lo, hi);
}

__device__ inline void acc8(float* a, uint4 v) {
  float2 f;
  f = bfp2f2(v.x); a[0]+=f.x; a[1]+=f.y;
  f = bfp2f2(v.y); a[2]+=f.x; a[3]+=f.y;
  f = bfp2f2(v.z); a[4]+=f.x; a[5]+=f.y;
  f = bfp2f2(v.w); a[6]+=f.x; a[7]+=f.y;
}

// ---------------- FUSED: aggregation (D=128) + MFMA GEMM (128 -> 128) ----------------
// Block = 256 threads = 4 waves, 64 dst rows. Phase A: quarter-wave gather into
// LDS As[64][132] fp32 (16 outstanding row loads/wave). Phase B: per-wave 16-row
// MFMA GEMM, A hi/lo split in-register. Kills the Ahi/Alo global round-trip.
__global__ __launch_bounds__(256) void agg_gemm_kernel(
    const uint4* __restrict__ hb4,      // gather src: N x 16 uint4 (bf16, dout-scaled)
    const int* __restrict__ rp, const int* __restrict__ col,
    const float* __restrict__ din_is,
    const uint4* __restrict__ Bhi, const uint4* __restrict__ Blo,  // Wt [128][128] bf16
    const float* __restrict__ bias, float* __restrict__ Out, int N) {
  __shared__ float As[64][132];   // +4 pad: LDS bank spread
  int wave = threadIdx.x >> 6;
  int lane = threadIdx.x & 63;
  int quad = lane >> 4, j = lane & 15;
  int row0 = blockIdx.x * 64;
  // ---- Phase A ----
  #pragma unroll
  for (int rr = 0; rr < 4; ++rr) {
    int dl = wave*16 + rr*4 + quad;
    int d  = row0 + dl;
    float a[8] = {0.f,0.f,0.f,0.f,0.f,0.f,0.f,0.f};
    float di = 0.f;
    if (d < N) {
      int s0 = rp[d], s1 = rp[d+1];
      di = din_is[d];
      int e = s0;
      for (; e + 4 <= s1; e += 4) {
        int c0 = col[e], c1 = col[e+1], c2 = col[e+2], c3 = col[e+3];
        uint4 v0 = hb4[(size_t)c0*16 + j];
        uint4 v1 = hb4[(size_t)c1*16 + j];
        uint4 v2 = hb4[(size_t)c2*16 + j];
        uint4 v3 = hb4[(size_t)c3*16 + j];
        acc8(a, v0); acc8(a, v1); acc8(a, v2); acc8(a, v3);
      }
      for (; e < s1; ++e) acc8(a, hb4[(size_t)col[e]*16 + j]);
    }
    float4* dp = (float4*)&As[dl][j*8];
    dp[0] = make_float4(a[0]*di, a[1]*di, a[2]*di, a[3]*di);
    dp[1] = make_float4(a[4]*di, a[5]*di, a[6]*di, a[7]*di);
  }
  __syncthreads();
  // ---- Phase B ----
  floatx4 acc[8];
  #pragma unroll
  for (int ct = 0; ct < 8; ++ct) acc[ct] = (floatx4){0.f,0.f,0.f,0.f};
  int arow = wave*16 + j;
  #pragma unroll
  for (int kc = 0; kc < 4; ++kc) {
    const float* ap = &As[arow][kc*32 + quad*8];
    float4 f0 = *(const float4*)(ap);
    float4 f1 = *(const float4*)(ap + 4);
    uint4 H, L;
    hilo2(f0.x, f0.y, H.x, L.x);
    hilo2(f0.z, f0.w, H.y, L.y);
    hilo2(f1.x, f1.y, H.z, L.z);
    hilo2(f1.z, f1.w, H.w, L.w);
    bf16x8 ah = asbf(H), al = asbf(L);
    #pragma unroll
    for (int ct = 0; ct < 8; ++ct) {
      int nr = ct*16 + j;
      uint4 bh = Bhi[nr*16 + kc*4 + quad];
      uint4 bl = Blo[nr*16 + kc*4 + quad];
      acc[ct] = __builtin_amdgcn_mfma_f32_16x16x32_bf16(ah, asbf(bh), acc[ct], 0, 0, 0);
      acc[ct] = __builtin_amdgcn_mfma_f32_16x16x32_bf16(ah, asbf(bl), acc[ct], 0, 0, 0);
      acc[ct] = __builtin_amdgcn_mfma_f32_16x16x32_bf16(al, asbf(bh), acc[ct], 0, 0, 0);
    }
  }
  #pragma unroll
  for (int ct = 0; ct < 8; ++ct) {
    int colc = ct*16 + j;
    float bs = bias[colc];
    #pragma unroll
    for (int r = 0; r < 4; ++r) {
      int grow = row0 + wave*16 + quad*4 + r;
      if (grow < N) Out[(size_t)grow*128 + colc] = acc[ct][r] + bs;
    }
  }
}

// ---------------- FUSED: BN-apply + ReLU + MFMA GEMM (128 -> 40, bf16 out) ----------------
__global__ __launch_bounds__(256) void bn_gemm40_kernel(
    const float* __restrict__ A,        // pre-BN fp32 N x 128
    const float* __restrict__ colA, const float* __restrict__ colB,
    const uint4* __restrict__ Bhi, const uint4* __restrict__ Blo,  // Wt3 [48][128]
    const float* __restrict__ rowscale,
    unsigned short* __restrict__ OutB, int N) {
  int wave = threadIdx.x >> 6;
  int lane = threadIdx.x & 63;
  int quad = lane >> 4, j = lane & 15;
  int row0 = blockIdx.x * 64 + wave * 16;
  int row = row0 + j;
  int rl = row < N ? row : N - 1;
  floatx4 acc[3];
  #pragma unroll
  for (int ct = 0; ct < 3; ++ct) acc[ct] = (floatx4){0.f,0.f,0.f,0.f};
  #pragma unroll
  for (int kc = 0; kc < 4; ++kc) {
    const float* ap = A + (size_t)rl*128 + kc*32 + quad*8;
    float4 f0 = *(const float4*)(ap);
    float4 f1 = *(const float4*)(ap + 4);
    const float* ca = colA + kc*32 + quad*8;
    const float* cb = colB + kc*32 + quad*8;
    float4 a0 = *(const float4*)(ca), a1 = *(const float4*)(ca + 4);
    float4 b0 = *(const float4*)(cb), b1 = *(const float4*)(cb + 4);
    float y0 = fmaxf(f0.x*a0.x + b0.x, 0.f);
    float y1 = fmaxf(f0.y*a0.y + b0.y, 0.f);
    float y2 = fmaxf(f0.z*a0.z + b0.z, 0.f);
    float y3 = fmaxf(f0.w*a0.w + b0.w, 0.f);
    float y4 = fmaxf(f1.x*a1.x + b1.x, 0.f);
    float y5 = fmaxf(f1.y*a1.y + b1.y, 0.f);
    float y6 = fmaxf(f1.z*a1.z + b1.z, 0.f);
    float y7 = fmaxf(f1.w*a1.w + b1.w, 0.f);
    uint4 H, L;
    hilo2(y0, y1, H.x, L.x);
    hilo2(y2, y3, H.y, L.y);
    hilo2(y4, y5, H.z, L.z);
    hilo2(y6, y7, H.w, L.w);
    bf16x8 ah = asbf(H), al = asbf(L);
    #pragma unroll
    for (int ct = 0; ct < 3; ++ct) {
      int nr = ct*16 + j;
      uint4 bh = Bhi[nr*16 + kc*4 + quad];
      uint4 bl = Blo[nr*16 + kc*4 + quad];
      acc[ct] = __builtin_amdgcn_mfma_f32_16x16x32_bf16(ah, asbf(bh), acc[ct], 0, 0, 0);
      acc[ct] = __builtin_amdgcn_mfma_f32_16x16x32_bf16(ah, asbf(bl), acc[ct], 0, 0, 0);
      acc[ct] = __builtin_amdgcn_mfma_f32_16x16x32_bf16(al, asbf(bh), acc[ct], 0, 0, 0);
    }
  }
  #pragma unroll
  for (int r = 0; r < 4; ++r) {
    int grow = row0 + quad*4 + r;
    if (grow < N) {
      float sc = rowscale[grow];
      #pragma unroll
      for (int ct = 0; ct < 3; ++ct) {
        int colc = ct*16 + j;
        if (colc < 40) OutB[(size_t)grow*40 + colc] = f2bf(acc[ct][r] * sc);
      }
    }
  }
}

// ---------------- BatchNorm stats ----------------
__global__ void bn_reduce_kernel(const float* __restrict__ h, float* __restrict__ gsum,
                                 float* __restrict__ gsumsq, int N, int rpb) {
  int f = threadIdx.x;
  int r0 = blockIdx.x * rpb;
  int r1 = r0 + rpb; if (r1 > N) r1 = N;
  float s = 0.f, ss = 0.f;
  for (int r = r0; r < r1; ++r) {
    float v = h[(size_t)r*128 + f];
    s += v; ss += v*v;
  }
  atomicAdd(&gsum[f], s);
  atomicAdd(&gsumsq[f], ss);
}

__global__ void bn_params_kernel(const float* __restrict__ gsum, const float* __restrict__ gsumsq,
                                 const float* __restrict__ g, const float* __restrict__ be,
                                 float* __restrict__ colA, float* __restrict__ colB, float invN) {
  int f = threadIdx.x;
  float mu  = gsum[f] * invN;
  float var = gsumsq[f] * invN - mu*mu;
  if (var < 0.f) var = 0.f;
  float rs = rsqrtf(var + 1e-5f);
  float a = g[f] * rs;
  colA[f] = a;
  colB[f] = be[f] - mu*a;
}

// bf16 out, pre-scaled by dout_is (feeds the layer-2 gather)
__global__ void bn_apply_bf16_kernel(const float* __restrict__ raw, const float* __restrict__ colA,
                                     const float* __restrict__ colB, const float* __restrict__ dout_is,
                                     unsigned* __restrict__ outb, int n4) {
  int i = blockIdx.x * blockDim.x + threadIdx.x;
  if (i >= n4) return;
  float4 v = ((const float4*)raw)[i];
  int c4 = i & 31;
  int row = i >> 5;
  float sc = dout_is[row];
  float4 a = ((const float4*)colA)[c4];
  float4 b = ((const float4*)colB)[c4];
  float x0 = fmaxf(v.x*a.x + b.x, 0.f) * sc;
  float x1 = fmaxf(v.y*a.y + b.y, 0.f) * sc;
  float x2 = fmaxf(v.z*a.z + b.z, 0.f) * sc;
  float x3 = fmaxf(v.w*a.w + b.w, 0.f) * sc;
  unsigned lo = (unsigned)f2bf(x0) | ((unsigned)f2bf(x1) << 16);
  unsigned hi = (unsigned)f2bf(x2) | ((unsigned)f2bf(x3) << 16);
  ((uint2*)outb)[i] = make_uint2(lo, hi);
}

// ---------------- layer 3: aggregate 40-dim bf16 (pre-scaled) + bias + log_softmax ----------------
__global__ __launch_bounds__(256) void final_kernel(
    const unsigned* __restrict__ tb,
    const int* __restrict__ rp, const int* __restrict__ col,
    const float* __restrict__ din_is, const float* __restrict__ b3,
    float* __restrict__ out, int N) {
  int wave = (blockIdx.x * blockDim.x + threadIdx.x) >> 6;
  int g = (threadIdx.x >> 5) & 1;
  int j = threadIdx.x & 31;
  int d = wave * 2 + g;
  if (d >= N) return;
  bool act = (j < 20);
  int s0 = rp[d], s1 = rp[d+1];
  float a0 = 0.f, a1 = 0.f;
  int e = s0;
  for (; e + 4 <= s1; e += 4) {
    int c0 = col[e], c1 = col[e+1], c2 = col[e+2], c3 = col[e+3];
    unsigned u0 = act ? tb[(size_t)c0*20 + j] : 0u;
    unsigned u1 = act ? tb[(size_t)c1*20 + j] : 0u;
    unsigned u2 = act ? tb[(size_t)c2*20 + j] : 0u;
    unsigned u3 = act ? tb[(size_t)c3*20 + j] : 0u;
    float2 f0 = bfp2f2(u0), f1 = bfp2f2(u1), f2 = bfp2f2(u2), f3 = bfp2f2(u3);
    a0 += (f0.x + f1.x) + (f2.x + f3.x);
    a1 += (f0.y + f1.y) + (f2.y + f3.y);
  }
  for (; e < s1; ++e) {
    unsigned u = act ? tb[(size_t)col[e]*20 + j] : 0u;
    float2 f = bfp2f2(u);
    a0 += f.x; a1 += f.y;
  }
  float di = din_is[d];
  float z0 = act ? di*a0 + b3[2*j]   : -1e30f;
  float z1 = act ? di*a1 + b3[2*j+1] : -1e30f;
  float m = fmaxf(z0, z1);
  #pragma unroll
  for (int off=16; off>0; off>>=1) m = fmaxf(m, __shfl_xor(m, off, 32));
  float s = act ? (expf(z0-m) + expf(z1-m)) : 0.f;
  #pragma unroll
  for (int off=16; off>0; off>>=1) s += __shfl_xor(s, off, 32);
  float lg = logf(s);
  if (act) {
    float2 o = make_float2(z0 - m - lg, z1 - m - lg);
    ((float2*)(out + (size_t)d*40))[j] = o;
  }
}

// ---------------- host ----------------
extern "C" void kernel_launch(void* const* d_in, const int* in_sizes, int n_in,
                              void* d_out, int out_size, void* d_ws, size_t ws_size,
                              hipStream_t stream) {
  const float* x   = (const float*)d_in[0];
  const int*   src = (const int*)d_in[1];
  const int*   dst = (const int*)d_in[2];
  const float* W1  = (const float*)d_in[3];
  const float* b1  = (const float*)d_in[4];
  const float* g1  = (const float*)d_in[5];
  const float* be1 = (const float*)d_in[6];
  const float* W2  = (const float*)d_in[7];
  const float* b2  = (const float*)d_in[8];
  const float* g2  = (const float*)d_in[9];
  const float* be2 = (const float*)d_in[10];
  const float* W3  = (const float*)d_in[11];
  const float* b3  = (const float*)d_in[12];
  const int E = in_sizes[1];
  const int D = in_sizes[4];     // 128
  const int N = in_sizes[0] / D; // 100000
  float* out = (float*)d_out;

  char* p = (char*)d_ws;
  auto alloc = [&](size_t bytes) { char* q = p; p += (bytes + 255) & ~(size_t)255; return q; };
  int* rp        = (int*)alloc((size_t)(N+1)*4);
  int* cnt_out   = (int*)alloc((size_t)N*4);
  float* din_is  = (float*)alloc((size_t)N*4);
  float* dout_is = (float*)alloc((size_t)N*4);
  float* gsum    = (float*)alloc((size_t)D*4);
  float* gsumsq  = (float*)alloc((size_t)D*4);
  float* colAp   = (float*)alloc((size_t)D*4);
  float* colBp   = (float*)alloc((size_t)D*4);
  int* bcnt      = (int*)alloc((size_t)MAXNB*4);
  int* bbase     = (int*)alloc((size_t)(MAXNB+1)*4);
  int* bcur      = (int*)alloc((size_t)MAXNB*4);
  unsigned short* Wt1hi = (unsigned short*)alloc(128*128*2);
  unsigned short* Wt1lo = (unsigned short*)alloc(128*128*2);
  unsigned short* Wt2hi = (unsigned short*)alloc(128*128*2);
  unsigned short* Wt2lo = (unsigned short*)alloc(128*128*2);
  unsigned short* Wt3hi = (unsigned short*)alloc(48*128*2);
  unsigned short* Wt3lo = (unsigned short*)alloc(48*128*2);
  int*   col     = (int*)alloc((size_t)E*4);
  float* bufA    = (float*)alloc((size_t)N*D*4);      // fp32 GEMM output
  unsigned* bf16buf = (unsigned*)alloc((size_t)N*D*2);
  // ebuf aliases bufA: CSR build finishes before bufA's first write
  uint2* ebuf = (uint2*)bufA;

  const int NB = (N + 255) >> 8;
  int nbN = (N + 255)/256;
  int cntB = (E + BCH_CNT - 1)/BCH_CNT;
  int binB = (E + BCH_BIN - 1)/BCH_BIN;

  hipMemsetAsync(cnt_out, 0, (size_t)N*4, stream);
  hipMemsetAsync(bcnt, 0, (size_t)MAXNB*4, stream);
  wt_hilo_kernel<<<(128*128+255)/256, 256, 0, stream>>>(W1, Wt1hi, Wt1lo, 128, 128);
  wt_hilo_kernel<<<(128*128+255)/256, 256, 0, stream>>>(W2, Wt2hi, Wt2lo, 128, 128);
  wt_hilo_kernel<<<(48*128+255)/256, 256, 0, stream>>>(W3, Wt3hi, Wt3lo, 40, 48);
  bucket_count_kernel<<<cntB, 256, 0, stream>>>(src, dst, bcnt, cnt_out, E, NB);
  invsqrt_dout_kernel<<<nbN, 256, 0, stream>>>(cnt_out, dout_is, N);
  bucket_scan_kernel<<<1, 256, 0, stream>>>(bcnt, bbase, bcur, rp, NB, N, E);
  bin_kernel<<<binB, 256, 0, stream>>>(src, dst, bcur, ebuf, E, NB);
  finalize_kernel<<<NB, 256, 0, stream>>>(ebuf, bbase, rp, din_is, col, N);

  int finb = ((N + 1)/2*64 + 255)/256;    // 2 dst per wave
  int gemb = (N + 63)/64;                 // 64 rows per block
  int rpb  = (N + 511)/512;
  int nel4 = (N*D)/4;

  // layer 1
  cast_scale_kernel<<<(nel4+255)/256, 256, 0, stream>>>(x, dout_is, bf16buf, nel4);
  agg_gemm_kernel<<<gemb, 256, 0, stream>>>((const uint4*)bf16buf, rp, col, din_is,
                                            (const uint4*)Wt1hi, (const uint4*)Wt1lo, b1, bufA, N);
  hipMemsetAsync(gsum, 0, (size_t)D*4, stream);
  hipMemsetAsync(gsumsq, 0, (size_t)D*4, stream);
  bn_reduce_kernel<<<512, 128, 0, stream>>>(bufA, gsum, gsumsq, N, rpb);
  bn_params_kernel<<<1, 128, 0, stream>>>(gsum, gsumsq, g1, be1, colAp, colBp, 1.0f/(float)N);
  bn_apply_bf16_kernel<<<(nel4+255)/256, 256, 0, stream>>>(bufA, colAp, colBp, dout_is, bf16buf, nel4);

  // layer 2
  agg_gemm_kernel<<<gemb, 256, 0, stream>>>((const uint4*)bf16buf, rp, col, din_is,
                                            (const uint4*)Wt2hi, (const uint4*)Wt2lo, b2, bufA, N);
  hipMemsetAsync(gsum, 0, (size_t)D*4, stream);
  hipMemsetAsync(gsumsq, 0, (size_t)D*4, stream);
  bn_reduce_kernel<<<512, 128, 0, stream>>>(bufA, gsum, gsumsq, N, rpb);
  bn_params_kernel<<<1, 128, 0, stream>>>(gsum, gsumsq, g2, be2, colAp, colBp, 1.0f/(float)N);

  // layer 3: fused BN + GEMM to 40 dims (bf16 out pre-scaled by dout), then agg + softmax
  bn_gemm40_kernel<<<gemb, 256, 0, stream>>>(bufA, colAp, colBp,
                                             (const uint4*)Wt3hi, (const uint4*)Wt3lo,
                                             dout_is, (unsigned short*)bf16buf, N);
  final_kernel<<<finb, 256, 0, stream>>>((const unsigned*)bf16buf, rp, col, din_is, b3, out, N);
}

// Round 8
// 729.924 us; speedup vs baseline: 1.0448x; 1.0177x over previous
//
#include <hip/hip_runtime.h>
#include <math.h>

#define MAXNB 1024    // max buckets (N <= 262144 with 256 nodes/bucket)
#define BCH_CNT 2048  // edges per block in count kernel
#define BCH_BIN 2048  // edges per block in bin kernel
#define BCAP  16384   // per-bucket edge capacity in finalize (mean 4096)

typedef __attribute__((ext_vector_type(8))) __bf16 bf16x8;
typedef __attribute__((ext_vector_type(4))) float floatx4;

__device__ inline bf16x8 asbf(uint4 u) {
  union { uint4 u; bf16x8 b; } c; c.u = u; return c.b;
}

// ---------- bf16 helpers ----------
__device__ inline unsigned short f2bf(float f) {
  union { float f; unsigned u; } v; v.f = f;
  unsigned r = v.u + 0x7fffu + ((v.u >> 16) & 1u);   // round-to-nearest-even
  return (unsigned short)(r >> 16);
}
__device__ inline float bf2f(unsigned short u) {
  union { unsigned u; float f; } v; v.u = ((unsigned)u) << 16;
  return v.f;
}
__device__ inline float2 bfp2f2(unsigned u) {       // packed bf16x2 -> float2
  union { unsigned u; float f; } a, b;
  a.u = u << 16;
  b.u = u & 0xffff0000u;
  float2 r; r.x = a.f; r.y = b.f; return r;
}
// split v into hi=bf16(v), lo=bf16(v-hi); packed pair for 2 values
__device__ inline void hilo2(float v0, float v1, unsigned& h, unsigned& l) {
  unsigned short h0 = f2bf(v0); float r0 = v0 - bf2f(h0);
  unsigned short h1 = f2bf(v1); float r1 = v1 - bf2f(h1);
  h = (unsigned)h0 | ((unsigned)h1 << 16);
  l = (unsigned)f2bf(r0) | ((unsigned)f2bf(r1) << 16);
}

// ---------------- CSR build: bucketed two-pass sort ----------------
__global__ __launch_bounds__(256) void bucket_count_kernel(
    const int* __restrict__ src, const int* __restrict__ dst,
    int* __restrict__ bcnt, int* __restrict__ cnt_out, int E, int NB) {
  __shared__ int hist[MAXNB];
  int tid = threadIdx.x;
  for (int i = tid; i < MAXNB; i += 256) hist[i] = 0;
  __syncthreads();
  int e0 = blockIdx.x * BCH_CNT;
  #pragma unroll
  for (int k = 0; k < BCH_CNT/256; ++k) {
    int e = e0 + k*256 + tid;
    if (e < E) {
      atomicAdd(&hist[dst[e] >> 8], 1);
      atomicAdd(&cnt_out[src[e]], 1);
    }
  }
  __syncthreads();
  for (int i = tid; i < NB; i += 256)
    if (hist[i]) atomicAdd(&bcnt[i], hist[i]);
}

__global__ __launch_bounds__(256) void bucket_scan_kernel(
    const int* __restrict__ bcnt, int* __restrict__ bbase, int* __restrict__ bcur,
    int* __restrict__ rp, int NB, int N, int E) {
  __shared__ int sh[256];
  int t = threadIdx.x;
  int base = t * 4;
  int v0 = (base+0 < NB) ? bcnt[base+0] : 0;
  int v1 = (base+1 < NB) ? bcnt[base+1] : 0;
  int v2 = (base+2 < NB) ? bcnt[base+2] : 0;
  int v3 = (base+3 < NB) ? bcnt[base+3] : 0;
  int s = v0+v1+v2+v3;
  sh[t] = s;
  __syncthreads();
  for (int off=1; off<256; off<<=1){
    int x = (t >= off) ? sh[t-off] : 0;
    __syncthreads();
    sh[t] += x;
    __syncthreads();
  }
  int run = sh[t] - s;
  if (base+0 <= NB) { bbase[base+0] = run; if (base+0 < NB) bcur[base+0] = run; } run += v0;
  if (base+1 <= NB) { bbase[base+1] = run; if (base+1 < NB) bcur[base+1] = run; } run += v1;
  if (base+2 <= NB) { bbase[base+2] = run; if (base+2 < NB) bcur[base+2] = run; } run += v2;
  if (base+3 <= NB) { bbase[base+3] = run; if (base+3 < NB) bcur[base+3] = run; }
  if (t == 0) rp[N] = E;
}

__global__ __launch_bounds__(256) void bin_kernel(
    const int* __restrict__ src, const int* __restrict__ dst,
    int* __restrict__ bcur, uint2* __restrict__ ebuf, int E, int NB) {
  __shared__ int hist[MAXNB];
  __shared__ int scanb[MAXNB];
  __shared__ int rbase[MAXNB];
  __shared__ int lcur[MAXNB];
  __shared__ int tmp[256];
  __shared__ uint2 stage[BCH_BIN];
  int tid = threadIdx.x;
  int e0 = blockIdx.x * BCH_BIN;
  int nedge = E - e0; if (nedge > BCH_BIN) nedge = BCH_BIN; if (nedge < 0) nedge = 0;
  for (int i = tid; i < MAXNB; i += 256) hist[i] = 0;
  __syncthreads();
  #pragma unroll
  for (int k = 0; k < BCH_BIN/256; ++k) {
    int e = e0 + k*256 + tid;
    if (e < E) atomicAdd(&hist[dst[e] >> 8], 1);
  }
  __syncthreads();
  {
    int base = tid * 4;
    int v0 = hist[base+0], v1 = hist[base+1], v2 = hist[base+2], v3 = hist[base+3];
    int s = v0+v1+v2+v3;
    tmp[tid] = s;
    __syncthreads();
    for (int off=1; off<256; off<<=1){
      int x = (tid >= off) ? tmp[tid-off] : 0;
      __syncthreads();
      tmp[tid] += x;
      __syncthreads();
    }
    int run = tmp[tid] - s;
    scanb[base+0] = run; run += v0;
    scanb[base+1] = run; run += v1;
    scanb[base+2] = run; run += v2;
    scanb[base+3] = run;
  }
  __syncthreads();
  for (int i = tid; i < NB; i += 256) {
    int h = hist[i];
    rbase[i] = h ? atomicAdd(&bcur[i], h) : 0;
    lcur[i] = scanb[i];
  }
  __syncthreads();
  #pragma unroll
  for (int k = 0; k < BCH_BIN/256; ++k) {
    int e = e0 + k*256 + tid;
    if (e < E) {
      int d = dst[e];
      int b = d >> 8;
      int p = atomicAdd(&lcur[b], 1);
      stage[p] = make_uint2((unsigned)src[e], (unsigned)d);
    }
  }
  __syncthreads();
  for (int i = tid; i < nedge; i += 256) {
    uint2 ed = stage[i];
    int b = (int)(ed.y >> 8);
    ebuf[rbase[b] + (i - scanb[b])] = ed;
  }
}

__global__ __launch_bounds__(256) void finalize_kernel(
    const uint2* __restrict__ ebuf, const int* __restrict__ bbase,
    int* __restrict__ rp, float* __restrict__ din_is,
    int* __restrict__ col, int N) {
  __shared__ int lcnt[256];
  __shared__ int lrp[257];
  __shared__ int lcur[256];
  __shared__ int tmp[256];
  __shared__ int colbuf[BCAP];
  int b = blockIdx.x;
  int tid = threadIdx.x;
  int node0 = b << 8;
  int e0 = bbase[b], e1 = bbase[b+1];
  int ne = e1 - e0;
  lcnt[tid] = 0;
  __syncthreads();
  for (int i = tid; i < ne; i += 256)
    atomicAdd(&lcnt[ebuf[e0+i].y & 255], 1);
  __syncthreads();
  int c = lcnt[tid];
  tmp[tid] = c;
  __syncthreads();
  for (int off=1; off<256; off<<=1){
    int x = (tid >= off) ? tmp[tid-off] : 0;
    __syncthreads();
    tmp[tid] += x;
    __syncthreads();
  }
  lrp[tid] = tmp[tid] - c;
  lcur[tid] = tmp[tid] - c;
  if (tid == 255) lrp[256] = tmp[255];
  __syncthreads();
  int node = node0 + tid;
  if (node < N) {
    rp[node] = e0 + lrp[tid];
    int cc = c < 1 ? 1 : c;
    din_is[node] = rsqrtf((float)cc);
  }
  if (ne <= BCAP) {
    for (int i = tid; i < ne; i += 256) {
      uint2 ed = ebuf[e0+i];
      int p = atomicAdd(&lcur[ed.y & 255], 1);
      colbuf[p] = (int)ed.x;
    }
    __syncthreads();
    for (int i = tid; i < ne; i += 256) col[e0+i] = colbuf[i];
  } else {
    for (int i = tid; i < ne; i += 256) {
      uint2 ed = ebuf[e0+i];
      int p = atomicAdd(&lcur[ed.y & 255], 1);
      col[e0+p] = (int)ed.x;
    }
  }
}

__global__ void invsqrt_dout_kernel(const int* __restrict__ cout,
                                    float* __restrict__ dout_is, int N) {
  int i = blockIdx.x * blockDim.x + threadIdx.x;
  if (i < N) {
    int b = cout[i]; if (b < 1) b = 1;
    dout_is[i] = rsqrtf((float)b);
  }
}

// ---------------- W -> transposed bf16 hi/lo: Wt[n][k], padded to npad rows ----------------
__global__ void wt_hilo_kernel(const float* __restrict__ W, unsigned short* __restrict__ Wthi,
                               unsigned short* __restrict__ Wtlo, int nreal, int npad) {
  int idx = blockIdx.x * blockDim.x + threadIdx.x;
  if (idx >= npad * 128) return;
  int n = idx >> 7;
  int k = idx & 127;
  float v = (n < nreal) ? W[k * nreal + n] : 0.f;
  unsigned short h = f2bf(v);
  float r = v - bf2f(h);
  Wthi[idx] = h;
  Wtlo[idx] = f2bf(r);
}

// ---------------- cast x (fp32 row) -> bf16 row pre-scaled by dout_is ----------------
__global__ void cast_scale_kernel(const float* __restrict__ x, const float* __restrict__ dout_is,
                                  unsigned* __restrict__ xb2, int n4) {
  int i = blockIdx.x * blockDim.x + threadIdx.x;
  if (i >= n4) return;
  float4 v = ((const float4*)x)[i];
  int row = i >> 5;
  float sc = dout_is[row];
  unsigned lo = (unsigned)f2bf(v.x * sc) | ((unsigned)f2bf(v.y * sc) << 16);
  unsigned hi = (unsigned)f2bf(v.z * sc) | ((unsigned)f2bf(v.w * sc) << 16);
  ((uint2*)xb2)[i] = make_uint2(lo, hi);
}

__device__ inline void acc8(float* a, uint4 v) {
  float2 f;
  f = bfp2f2(v.x); a[0]+=f.x; a[1]+=f.y;
  f = bfp2f2(v.y); a[2]+=f.x; a[3]+=f.y;
  f = bfp2f2(v.z); a[4]+=f.x; a[5]+=f.y;
  f = bfp2f2(v.w); a[6]+=f.x; a[7]+=f.y;
}

// ---------------- aggregation over bf16 rows (dout-prescaled), D=128, fp32 out ----------------
// Quarter-wave per dst row, 8-deep unroll (8 vmem in flight per lane), no LDS.
__global__ __launch_bounds__(256) void agg128_kernel(
    const uint4* __restrict__ hb4,
    const int* __restrict__ rp, const int* __restrict__ col,
    const float* __restrict__ din_is, float* __restrict__ out, int N) {
  int wave = (blockIdx.x * blockDim.x + threadIdx.x) >> 6;
  int lane = threadIdx.x & 63;
  int g = lane >> 4, j = lane & 15;
  int d = wave * 4 + g;
  if (d >= N) return;
  int s0 = rp[d], s1 = rp[d+1];
  float a[8] = {0.f,0.f,0.f,0.f,0.f,0.f,0.f,0.f};
  int e = s0;
  for (; e + 8 <= s1; e += 8) {
    int c0 = col[e],   c1 = col[e+1], c2 = col[e+2], c3 = col[e+3];
    int c4 = col[e+4], c5 = col[e+5], c6 = col[e+6], c7 = col[e+7];
    uint4 v0 = hb4[(size_t)c0*16 + j];
    uint4 v1 = hb4[(size_t)c1*16 + j];
    uint4 v2 = hb4[(size_t)c2*16 + j];
    uint4 v3 = hb4[(size_t)c3*16 + j];
    uint4 v4 = hb4[(size_t)c4*16 + j];
    uint4 v5 = hb4[(size_t)c5*16 + j];
    uint4 v6 = hb4[(size_t)c6*16 + j];
    uint4 v7 = hb4[(size_t)c7*16 + j];
    acc8(a, v0); acc8(a, v1); acc8(a, v2); acc8(a, v3);
    acc8(a, v4); acc8(a, v5); acc8(a, v6); acc8(a, v7);
  }
  for (; e + 4 <= s1; e += 4) {
    int c0 = col[e], c1 = col[e+1], c2 = col[e+2], c3 = col[e+3];
    uint4 v0 = hb4[(size_t)c0*16 + j];
    uint4 v1 = hb4[(size_t)c1*16 + j];
    uint4 v2 = hb4[(size_t)c2*16 + j];
    uint4 v3 = hb4[(size_t)c3*16 + j];
    acc8(a, v0); acc8(a, v1); acc8(a, v2); acc8(a, v3);
  }
  for (; e < s1; ++e) acc8(a, hb4[(size_t)col[e]*16 + j]);
  float di = din_is[d];
  float4* ob = (float4*)out + (size_t)d*32 + 2*j;
  ob[0] = make_float4(a[0]*di, a[1]*di, a[2]*di, a[3]*di);
  ob[1] = make_float4(a[4]*di, a[5]*di, a[6]*di, a[7]*di);
}

// ---------------- MFMA GEMM 128->128: A fp32 (hi/lo split in-register), +bias ----------------
__global__ __launch_bounds__(256) void gemm128_kernel(
    const float* __restrict__ A,
    const uint4* __restrict__ Bhi, const uint4* __restrict__ Blo,  // Wt [128][128] bf16
    const float* __restrict__ bias, float* __restrict__ Out, int N) {
  int wave = threadIdx.x >> 6;
  int lane = threadIdx.x & 63;
  int quad = lane >> 4, j = lane & 15;
  int row0 = blockIdx.x * 64 + wave * 16;
  int row = row0 + j;
  int rl = row < N ? row : N - 1;
  floatx4 acc[8];
  #pragma unroll
  for (int ct = 0; ct < 8; ++ct) acc[ct] = (floatx4){0.f,0.f,0.f,0.f};
  #pragma unroll
  for (int kc = 0; kc < 4; ++kc) {
    const float* ap = A + (size_t)rl*128 + kc*32 + quad*8;
    float4 f0 = *(const float4*)(ap);
    float4 f1 = *(const float4*)(ap + 4);
    uint4 H, L;
    hilo2(f0.x, f0.y, H.x, L.x);
    hilo2(f0.z, f0.w, H.y, L.y);
    hilo2(f1.x, f1.y, H.z, L.z);
    hilo2(f1.z, f1.w, H.w, L.w);
    bf16x8 ah = asbf(H), al = asbf(L);
    #pragma unroll
    for (int ct = 0; ct < 8; ++ct) {
      int nr = ct*16 + j;
      uint4 bh = Bhi[nr*16 + kc*4 + quad];
      uint4 bl = Blo[nr*16 + kc*4 + quad];
      acc[ct] = __builtin_amdgcn_mfma_f32_16x16x32_bf16(ah, asbf(bh), acc[ct], 0, 0, 0);
      acc[ct] = __builtin_amdgcn_mfma_f32_16x16x32_bf16(ah, asbf(bl), acc[ct], 0, 0, 0);
      acc[ct] = __builtin_amdgcn_mfma_f32_16x16x32_bf16(al, asbf(bh), acc[ct], 0, 0, 0);
    }
  }
  #pragma unroll
  for (int ct = 0; ct < 8; ++ct) {
    int colc = ct*16 + j;
    float bs = bias[colc];
    #pragma unroll
    for (int r = 0; r < 4; ++r) {
      int grow = row0 + quad*4 + r;
      if (grow < N) Out[(size_t)grow*128 + colc] = acc[ct][r] + bs;
    }
  }
}

// ---------------- FUSED: BN-apply + ReLU + MFMA GEMM (128 -> 40, bf16 out) ----------------
__global__ __launch_bounds__(256) void bn_gemm40_kernel(
    const float* __restrict__ A,
    const float* __restrict__ colA, const float* __restrict__ colB,
    const uint4* __restrict__ Bhi, const uint4* __restrict__ Blo,  // Wt3 [48][128]
    const float* __restrict__ rowscale,
    unsigned short* __restrict__ OutB, int N) {
  int wave = threadIdx.x >> 6;
  int lane = threadIdx.x & 63;
  int quad = lane >> 4, j = lane & 15;
  int row0 = blockIdx.x * 64 + wave * 16;
  int row = row0 + j;
  int rl = row < N ? row : N - 1;
  floatx4 acc[3];
  #pragma unroll
  for (int ct = 0; ct < 3; ++ct) acc[ct] = (floatx4){0.f,0.f,0.f,0.f};
  #pragma unroll
  for (int kc = 0; kc < 4; ++kc) {
    const float* ap = A + (size_t)rl*128 + kc*32 + quad*8;
    float4 f0 = *(const float4*)(ap);
    float4 f1 = *(const float4*)(ap + 4);
    const float* ca = colA + kc*32 + quad*8;
    const float* cb = colB + kc*32 + quad*8;
    float4 a0 = *(const float4*)(ca), a1 = *(const float4*)(ca + 4);
    float4 b0 = *(const float4*)(cb), b1 = *(const float4*)(cb + 4);
    float y0 = fmaxf(f0.x*a0.x + b0.x, 0.f);
    float y1 = fmaxf(f0.y*a0.y + b0.y, 0.f);
    float y2 = fmaxf(f0.z*a0.z + b0.z, 0.f);
    float y3 = fmaxf(f0.w*a0.w + b0.w, 0.f);
    float y4 = fmaxf(f1.x*a1.x + b1.x, 0.f);
    float y5 = fmaxf(f1.y*a1.y + b1.y, 0.f);
    float y6 = fmaxf(f1.z*a1.z + b1.z, 0.f);
    float y7 = fmaxf(f1.w*a1.w + b1.w, 0.f);
    uint4 H, L;
    hilo2(y0, y1, H.x, L.x);
    hilo2(y2, y3, H.y, L.y);
    hilo2(y4, y5, H.z, L.z);
    hilo2(y6, y7, H.w, L.w);
    bf16x8 ah = asbf(H), al = asbf(L);
    #pragma unroll
    for (int ct = 0; ct < 3; ++ct) {
      int nr = ct*16 + j;
      uint4 bh = Bhi[nr*16 + kc*4 + quad];
      uint4 bl = Blo[nr*16 + kc*4 + quad];
      acc[ct] = __builtin_amdgcn_mfma_f32_16x16x32_bf16(ah, asbf(bh), acc[ct], 0, 0, 0);
      acc[ct] = __builtin_amdgcn_mfma_f32_16x16x32_bf16(ah, asbf(bl), acc[ct], 0, 0, 0);
      acc[ct] = __builtin_amdgcn_mfma_f32_16x16x32_bf16(al, asbf(bh), acc[ct], 0, 0, 0);
    }
  }
  #pragma unroll
  for (int r = 0; r < 4; ++r) {
    int grow = row0 + quad*4 + r;
    if (grow < N) {
      float sc = rowscale[grow];
      #pragma unroll
      for (int ct = 0; ct < 3; ++ct) {
        int colc = ct*16 + j;
        if (colc < 40) OutB[(size_t)grow*40 + colc] = f2bf(acc[ct][r] * sc);
      }
    }
  }
}

// ---------------- BatchNorm stats ----------------
__global__ void bn_reduce_kernel(const float* __restrict__ h, float* __restrict__ gsum,
                                 float* __restrict__ gsumsq, int N, int rpb) {
  int f = threadIdx.x;
  int r0 = blockIdx.x * rpb;
  int r1 = r0 + rpb; if (r1 > N) r1 = N;
  float s = 0.f, ss = 0.f;
  for (int r = r0; r < r1; ++r) {
    float v = h[(size_t)r*128 + f];
    s += v; ss += v*v;
  }
  atomicAdd(&gsum[f], s);
  atomicAdd(&gsumsq[f], ss);
}

__global__ void bn_params_kernel(const float* __restrict__ gsum, const float* __restrict__ gsumsq,
                                 const float* __restrict__ g, const float* __restrict__ be,
                                 float* __restrict__ colA, float* __restrict__ colB, float invN) {
  int f = threadIdx.x;
  float mu  = gsum[f] * invN;
  float var = gsumsq[f] * invN - mu*mu;
  if (var < 0.f) var = 0.f;
  float rs = rsqrtf(var + 1e-5f);
  float a = g[f] * rs;
  colA[f] = a;
  colB[f] = be[f] - mu*a;
}

// bf16 out, pre-scaled by dout_is (feeds the layer-2 gather)
__global__ void bn_apply_bf16_kernel(const float* __restrict__ raw, const float* __restrict__ colA,
                                     const float* __restrict__ colB, const float* __restrict__ dout_is,
                                     unsigned* __restrict__ outb, int n4) {
  int i = blockIdx.x * blockDim.x + threadIdx.x;
  if (i >= n4) return;
  float4 v = ((const float4*)raw)[i];
  int c4 = i & 31;
  int row = i >> 5;
  float sc = dout_is[row];
  float4 a = ((const float4*)colA)[c4];
  float4 b = ((const float4*)colB)[c4];
  float x0 = fmaxf(v.x*a.x + b.x, 0.f) * sc;
  float x1 = fmaxf(v.y*a.y + b.y, 0.f) * sc;
  float x2 = fmaxf(v.z*a.z + b.z, 0.f) * sc;
  float x3 = fmaxf(v.w*a.w + b.w, 0.f) * sc;
  unsigned lo = (unsigned)f2bf(x0) | ((unsigned)f2bf(x1) << 16);
  unsigned hi = (unsigned)f2bf(x2) | ((unsigned)f2bf(x3) << 16);
  ((uint2*)outb)[i] = make_uint2(lo, hi);
}

// ---------------- layer 3: aggregate 40-dim bf16 (pre-scaled) + bias + log_softmax ----------------
__global__ __launch_bounds__(256) void final_kernel(
    const unsigned* __restrict__ tb,
    const int* __restrict__ rp, const int* __restrict__ col,
    const float* __restrict__ din_is, const float* __restrict__ b3,
    float* __restrict__ out, int N) {
  int wave = (blockIdx.x * blockDim.x + threadIdx.x) >> 6;
  int g = (threadIdx.x >> 5) & 1;
  int j = threadIdx.x & 31;
  int d = wave * 2 + g;
  if (d >= N) return;
  bool act = (j < 20);
  int s0 = rp[d], s1 = rp[d+1];
  float a0 = 0.f, a1 = 0.f;
  int e = s0;
  for (; e + 8 <= s1; e += 8) {
    int c0 = col[e],   c1 = col[e+1], c2 = col[e+2], c3 = col[e+3];
    int c4 = col[e+4], c5 = col[e+5], c6 = col[e+6], c7 = col[e+7];
    unsigned u0 = act ? tb[(size_t)c0*20 + j] : 0u;
    unsigned u1 = act ? tb[(size_t)c1*20 + j] : 0u;
    unsigned u2 = act ? tb[(size_t)c2*20 + j] : 0u;
    unsigned u3 = act ? tb[(size_t)c3*20 + j] : 0u;
    unsigned u4 = act ? tb[(size_t)c4*20 + j] : 0u;
    unsigned u5 = act ? tb[(size_t)c5*20 + j] : 0u;
    unsigned u6 = act ? tb[(size_t)c6*20 + j] : 0u;
    unsigned u7 = act ? tb[(size_t)c7*20 + j] : 0u;
    float2 f0 = bfp2f2(u0), f1 = bfp2f2(u1), f2 = bfp2f2(u2), f3 = bfp2f2(u3);
    float2 f4 = bfp2f2(u4), f5 = bfp2f2(u5), f6 = bfp2f2(u6), f7 = bfp2f2(u7);
    a0 += ((f0.x + f1.x) + (f2.x + f3.x)) + ((f4.x + f5.x) + (f6.x + f7.x));
    a1 += ((f0.y + f1.y) + (f2.y + f3.y)) + ((f4.y + f5.y) + (f6.y + f7.y));
  }
  for (; e + 4 <= s1; e += 4) {
    int c0 = col[e], c1 = col[e+1], c2 = col[e+2], c3 = col[e+3];
    unsigned u0 = act ? tb[(size_t)c0*20 + j] : 0u;
    unsigned u1 = act ? tb[(size_t)c1*20 + j] : 0u;
    unsigned u2 = act ? tb[(size_t)c2*20 + j] : 0u;
    unsigned u3 = act ? tb[(size_t)c3*20 + j] : 0u;
    float2 f0 = bfp2f2(u0), f1 = bfp2f2(u1), f2 = bfp2f2(u2), f3 = bfp2f2(u3);
    a0 += (f0.x + f1.x) + (f2.x + f3.x);
    a1 += (f0.y + f1.y) + (f2.y + f3.y);
  }
  for (; e < s1; ++e) {
    unsigned u = act ? tb[(size_t)col[e]*20 + j] : 0u;
    float2 f = bfp2f2(u);
    a0 += f.x; a1 += f.y;
  }
  float di = din_is[d];
  float z0 = act ? di*a0 + b3[2*j]   : -1e30f;
  float z1 = act ? di*a1 + b3[2*j+1] : -1e30f;
  float m = fmaxf(z0, z1);
  #pragma unroll
  for (int off=16; off>0; off>>=1) m = fmaxf(m, __shfl_xor(m, off, 32));
  float s = act ? (expf(z0-m) + expf(z1-m)) : 0.f;
  #pragma unroll
  for (int off=16; off>0; off>>=1) s += __shfl_xor(s, off, 32);
  float lg = logf(s);
  if (act) {
    float2 o = make_float2(z0 - m - lg, z1 - m - lg);
    ((float2*)(out + (size_t)d*40))[j] = o;
  }
}

// ---------------- host ----------------
extern "C" void kernel_launch(void* const* d_in, const int* in_sizes, int n_in,
                              void* d_out, int out_size, void* d_ws, size_t ws_size,
                              hipStream_t stream) {
  const float* x   = (const float*)d_in[0];
  const int*   src = (const int*)d_in[1];
  const int*   dst = (const int*)d_in[2];
  const float* W1  = (const float*)d_in[3];
  const float* b1  = (const float*)d_in[4];
  const float* g1  = (const float*)d_in[5];
  const float* be1 = (const float*)d_in[6];
  const float* W2  = (const float*)d_in[7];
  const float* b2  = (const float*)d_in[8];
  const float* g2  = (const float*)d_in[9];
  const float* be2 = (const float*)d_in[10];
  const float* W3  = (const float*)d_in[11];
  const float* b3  = (const float*)d_in[12];
  const int E = in_sizes[1];
  const int D = in_sizes[4];     // 128
  const int N = in_sizes[0] / D; // 100000
  float* out = (float*)d_out;

  char* p = (char*)d_ws;
  auto alloc = [&](size_t bytes) { char* q = p; p += (bytes + 255) & ~(size_t)255; return q; };
  int* rp        = (int*)alloc((size_t)(N+1)*4);
  int* cnt_out   = (int*)alloc((size_t)N*4);
  float* din_is  = (float*)alloc((size_t)N*4);
  float* dout_is = (float*)alloc((size_t)N*4);
  float* gsum    = (float*)alloc((size_t)D*4);
  float* gsumsq  = (float*)alloc((size_t)D*4);
  float* colAp   = (float*)alloc((size_t)D*4);
  float* colBp   = (float*)alloc((size_t)D*4);
  int* bcnt      = (int*)alloc((size_t)MAXNB*4);
  int* bbase     = (int*)alloc((size_t)(MAXNB+1)*4);
  int* bcur      = (int*)alloc((size_t)MAXNB*4);
  unsigned short* Wt1hi = (unsigned short*)alloc(128*128*2);
  unsigned short* Wt1lo = (unsigned short*)alloc(128*128*2);
  unsigned short* Wt2hi = (unsigned short*)alloc(128*128*2);
  unsigned short* Wt2lo = (unsigned short*)alloc(128*128*2);
  unsigned short* Wt3hi = (unsigned short*)alloc(48*128*2);
  unsigned short* Wt3lo = (unsigned short*)alloc(48*128*2);
  int*   col     = (int*)alloc((size_t)E*4);
  float* bufA    = (float*)alloc((size_t)N*D*4);      // GEMM output (fp32)
  float* bufB    = (float*)alloc((size_t)N*D*4);      // agg output (fp32)
  unsigned* bf16buf = (unsigned*)alloc((size_t)N*D*2);
  // ebuf aliases bufA: CSR build finishes before bufA's first write (gemm128 out)
  uint2* ebuf = (uint2*)bufA;

  const int NB = (N + 255) >> 8;
  int nbN = (N + 255)/256;
  int cntB = (E + BCH_CNT - 1)/BCH_CNT;
  int binB = (E + BCH_BIN - 1)/BCH_BIN;

  hipMemsetAsync(cnt_out, 0, (size_t)N*4, stream);
  hipMemsetAsync(bcnt, 0, (size_t)MAXNB*4, stream);
  wt_hilo_kernel<<<(128*128+255)/256, 256, 0, stream>>>(W1, Wt1hi, Wt1lo, 128, 128);
  wt_hilo_kernel<<<(128*128+255)/256, 256, 0, stream>>>(W2, Wt2hi, Wt2lo, 128, 128);
  wt_hilo_kernel<<<(48*128+255)/256, 256, 0, stream>>>(W3, Wt3hi, Wt3lo, 40, 48);
  bucket_count_kernel<<<cntB, 256, 0, stream>>>(src, dst, bcnt, cnt_out, E, NB);
  invsqrt_dout_kernel<<<nbN, 256, 0, stream>>>(cnt_out, dout_is, N);
  bucket_scan_kernel<<<1, 256, 0, stream>>>(bcnt, bbase, bcur, rp, NB, N, E);
  bin_kernel<<<binB, 256, 0, stream>>>(src, dst, bcur, ebuf, E, NB);
  finalize_kernel<<<NB, 256, 0, stream>>>(ebuf, bbase, rp, din_is, col, N);

  int aggb = ((N + 3)/4*64 + 255)/256;    // 4 dst per wave
  int finb = ((N + 1)/2*64 + 255)/256;    // 2 dst per wave
  int gemb = (N + 63)/64;                 // 64 rows per block
  int rpb  = (N + 511)/512;
  int nel4 = (N*D)/4;

  // layer 1
  cast_scale_kernel<<<(nel4+255)/256, 256, 0, stream>>>(x, dout_is, bf16buf, nel4);
  agg128_kernel<<<aggb, 256, 0, stream>>>((const uint4*)bf16buf, rp, col, din_is, bufB, N);
  gemm128_kernel<<<gemb, 256, 0, stream>>>(bufB, (const uint4*)Wt1hi, (const uint4*)Wt1lo, b1, bufA, N);
  hipMemsetAsync(gsum, 0, (size_t)D*4, stream);
  hipMemsetAsync(gsumsq, 0, (size_t)D*4, stream);
  bn_reduce_kernel<<<512, 128, 0, stream>>>(bufA, gsum, gsumsq, N, rpb);
  bn_params_kernel<<<1, 128, 0, stream>>>(gsum, gsumsq, g1, be1, colAp, colBp, 1.0f/(float)N);
  bn_apply_bf16_kernel<<<(nel4+255)/256, 256, 0, stream>>>(bufA, colAp, colBp, dout_is, bf16buf, nel4);

  // layer 2
  agg128_kernel<<<aggb, 256, 0, stream>>>((const uint4*)bf16buf, rp, col, din_is, bufB, N);
  gemm128_kernel<<<gemb, 256, 0, stream>>>(bufB, (const uint4*)Wt2hi, (const uint4*)Wt2lo, b2, bufA, N);
  hipMemsetAsync(gsum, 0, (size_t)D*4, stream);
  hipMemsetAsync(gsumsq, 0, (size_t)D*4, stream);
  bn_reduce_kernel<<<512, 128, 0, stream>>>(bufA, gsum, gsumsq, N, rpb);
  bn_params_kernel<<<1, 128, 0, stream>>>(gsum, gsumsq, g2, be2, colAp, colBp, 1.0f/(float)N);

  // layer 3: fused BN + GEMM to 40 dims (bf16 out pre-scaled by dout), then agg + softmax
  bn_gemm40_kernel<<<gemb, 256, 0, stream>>>(bufA, colAp, colBp,
                                             (const uint4*)Wt3hi, (const uint4*)Wt3lo,
                                             dout_is, (unsigned short*)bf16buf, N);
  final_kernel<<<finb, 256, 0, stream>>>((const unsigned*)bf16buf, rp, col, din_is, b3, out, N);
}

// Round 9
// 712.552 us; speedup vs baseline: 1.0702x; 1.0244x over previous
//
#include <hip/hip_runtime.h>
#include <math.h>

#define MAXNB 1024    // max buckets (N <= 262144 with 256 nodes/bucket)
#define BCH_CNT 2048  // edges per block in count kernel
#define BCH_BIN 2048  // edges per block in bin kernels
#define BCAP  16384   // per-bucket edge capacity in finalize (mean 4096)

typedef __attribute__((ext_vector_type(8))) __bf16 bf16x8;
typedef __attribute__((ext_vector_type(4))) float floatx4;

__device__ inline bf16x8 asbf(uint4 u) {
  union { uint4 u; bf16x8 b; } c; c.u = u; return c.b;
}

// ---------- bf16 helpers ----------
__device__ inline unsigned short f2bf(float f) {
  union { float f; unsigned u; } v; v.f = f;
  unsigned r = v.u + 0x7fffu + ((v.u >> 16) & 1u);   // round-to-nearest-even
  return (unsigned short)(r >> 16);
}
__device__ inline float bf2f(unsigned short u) {
  union { unsigned u; float f; } v; v.u = ((unsigned)u) << 16;
  return v.f;
}
__device__ inline float2 bfp2f2(unsigned u) {       // packed bf16x2 -> float2
  union { unsigned u; float f; } a, b;
  a.u = u << 16;
  b.u = u & 0xffff0000u;
  float2 r; r.x = a.f; r.y = b.f; return r;
}
// split v into hi=bf16(v), lo=bf16(v-hi); packed pair for 2 values
__device__ inline void hilo2(float v0, float v1, unsigned& h, unsigned& l) {
  unsigned short h0 = f2bf(v0); float r0 = v0 - bf2f(h0);
  unsigned short h1 = f2bf(v1); float r1 = v1 - bf2f(h1);
  h = (unsigned)h0 | ((unsigned)h1 << 16);
  l = (unsigned)f2bf(r0) | ((unsigned)f2bf(r1) << 16);
}

// ---------------- CSR build: bucketed sorts for dst (CSR) and src (out-degree) ----------------
// C1: both bucket histograms in one coalesced pass; zero random atomics.
__global__ __launch_bounds__(256) void count2_kernel(
    const int* __restrict__ src, const int* __restrict__ dst,
    int* __restrict__ bcnt, int* __restrict__ scnt, int E, int NB) {
  __shared__ int histd[MAXNB];
  __shared__ int hists[MAXNB];
  int tid = threadIdx.x;
  for (int i = tid; i < MAXNB; i += 256) { histd[i] = 0; hists[i] = 0; }
  __syncthreads();
  int e0 = blockIdx.x * BCH_CNT;
  #pragma unroll
  for (int k = 0; k < BCH_CNT/256; ++k) {
    int e = e0 + k*256 + tid;
    if (e < E) {
      atomicAdd(&histd[dst[e] >> 8], 1);
      atomicAdd(&hists[src[e] >> 8], 1);
    }
  }
  __syncthreads();
  for (int i = tid; i < NB; i += 256) {
    if (histd[i]) atomicAdd(&bcnt[i], histd[i]);
    if (hists[i]) atomicAdd(&scnt[i], hists[i]);
  }
}

// C2: scan both bucket-count arrays; init cursors; rp[N]=E.
__global__ __launch_bounds__(256) void scan2_kernel(
    const int* __restrict__ bcnt, int* __restrict__ bbase, int* __restrict__ bcur,
    const int* __restrict__ scnt, int* __restrict__ sbase, int* __restrict__ scur,
    int* __restrict__ rp, int NB, int N, int E) {
  __shared__ int sh[256];
  int t = threadIdx.x;
  for (int pass = 0; pass < 2; ++pass) {
    const int* cnt = pass ? scnt : bcnt;
    int* base_ = pass ? sbase : bbase;
    int* cur_  = pass ? scur  : bcur;
    int base = t * 4;
    int v0 = (base+0 < NB) ? cnt[base+0] : 0;
    int v1 = (base+1 < NB) ? cnt[base+1] : 0;
    int v2 = (base+2 < NB) ? cnt[base+2] : 0;
    int v3 = (base+3 < NB) ? cnt[base+3] : 0;
    int s = v0+v1+v2+v3;
    sh[t] = s;
    __syncthreads();
    for (int off=1; off<256; off<<=1){
      int x = (t >= off) ? sh[t-off] : 0;
      __syncthreads();
      sh[t] += x;
      __syncthreads();
    }
    int run = sh[t] - s;
    if (base+0 <= NB) { base_[base+0] = run; if (base+0 < NB) cur_[base+0] = run; } run += v0;
    if (base+1 <= NB) { base_[base+1] = run; if (base+1 < NB) cur_[base+1] = run; } run += v1;
    if (base+2 <= NB) { base_[base+2] = run; if (base+2 < NB) cur_[base+2] = run; } run += v2;
    if (base+3 <= NB) { base_[base+3] = run; if (base+3 < NB) cur_[base+3] = run; }
    __syncthreads();
  }
  if (t == 0) rp[N] = E;
}

// C3a: bin by dst bucket; payload packed (dst&255)<<24 | src  (needs N < 2^24)
__global__ __launch_bounds__(256) void bin_dst_kernel(
    const int* __restrict__ src, const int* __restrict__ dst,
    int* __restrict__ bcur, unsigned* __restrict__ ebuf, int E, int NB) {
  __shared__ int hist[MAXNB];
  __shared__ int scanb[MAXNB];
  __shared__ int rbase[MAXNB];
  __shared__ int lcur[MAXNB];
  __shared__ int tmp[256];
  __shared__ unsigned stage[BCH_BIN];
  int tid = threadIdx.x;
  int e0 = blockIdx.x * BCH_BIN;
  int nedge = E - e0; if (nedge > BCH_BIN) nedge = BCH_BIN; if (nedge < 0) nedge = 0;
  for (int i = tid; i < MAXNB; i += 256) hist[i] = 0;
  __syncthreads();
  #pragma unroll
  for (int k = 0; k < BCH_BIN/256; ++k) {
    int e = e0 + k*256 + tid;
    if (e < E) atomicAdd(&hist[dst[e] >> 8], 1);
  }
  __syncthreads();
  {
    int base = tid * 4;
    int v0 = hist[base+0], v1 = hist[base+1], v2 = hist[base+2], v3 = hist[base+3];
    int s = v0+v1+v2+v3;
    tmp[tid] = s;
    __syncthreads();
    for (int off=1; off<256; off<<=1){
      int x = (tid >= off) ? tmp[tid-off] : 0;
      __syncthreads();
      tmp[tid] += x;
      __syncthreads();
    }
    int run = tmp[tid] - s;
    scanb[base+0] = run; run += v0;
    scanb[base+1] = run; run += v1;
    scanb[base+2] = run; run += v2;
    scanb[base+3] = run;
  }
  __syncthreads();
  for (int i = tid; i < NB; i += 256) {
    int h = hist[i];
    rbase[i] = h ? atomicAdd(&bcur[i], h) : 0;
    lcur[i] = scanb[i];
  }
  __syncthreads();
  #pragma unroll
  for (int k = 0; k < BCH_BIN/256; ++k) {
    int e = e0 + k*256 + tid;
    if (e < E) {
      int d = dst[e];
      int b = d >> 8;
      int p = atomicAdd(&lcur[b], 1);
      stage[p] = ((unsigned)(d & 255) << 24) | (unsigned)src[e];
    }
  }
  __syncthreads();
  // bucket id for slot i: binary-search-free — recover via scanb? Use stage payload only.
  for (int i = tid; i < nedge; i += 256) {
    unsigned ed = stage[i];
    // find bucket: we stored per-bucket contiguous runs; bucket of slot i is the
    // one whose scanb <= i < scanb+hist. Recover from dst low byte is NOT enough;
    // instead recompute via rbase lookup using a second pass structure:
    // we keep it simple: store bucket id in high bits? Not enough bits. Use
    // membership: since runs are contiguous and scanb is sorted, do a
    // galloping search over scanb (log2(MAXNB)=10 LDS reads, bank-friendly).
    int lo = 0, hi = NB - 1;
    while (lo < hi) {
      int mid = (lo + hi + 1) >> 1;
      if (scanb[mid] <= i) lo = mid; else hi = mid - 1;
    }
    ebuf[rbase[lo] + (i - scanb[lo])] = ed;
  }
}

// C3b: bin src values by src bucket (payload = src)
__global__ __launch_bounds__(256) void bin_src_kernel(
    const int* __restrict__ src,
    int* __restrict__ scur, unsigned* __restrict__ sbuf, int E, int NB) {
  __shared__ int hist[MAXNB];
  __shared__ int scanb[MAXNB];
  __shared__ int rbase[MAXNB];
  __shared__ int lcur[MAXNB];
  __shared__ int tmp[256];
  __shared__ unsigned stage[BCH_BIN];
  int tid = threadIdx.x;
  int e0 = blockIdx.x * BCH_BIN;
  int nedge = E - e0; if (nedge > BCH_BIN) nedge = BCH_BIN; if (nedge < 0) nedge = 0;
  for (int i = tid; i < MAXNB; i += 256) hist[i] = 0;
  __syncthreads();
  #pragma unroll
  for (int k = 0; k < BCH_BIN/256; ++k) {
    int e = e0 + k*256 + tid;
    if (e < E) atomicAdd(&hist[src[e] >> 8], 1);
  }
  __syncthreads();
  {
    int base = tid * 4;
    int v0 = hist[base+0], v1 = hist[base+1], v2 = hist[base+2], v3 = hist[base+3];
    int s = v0+v1+v2+v3;
    tmp[tid] = s;
    __syncthreads();
    for (int off=1; off<256; off<<=1){
      int x = (tid >= off) ? tmp[tid-off] : 0;
      __syncthreads();
      tmp[tid] += x;
      __syncthreads();
    }
    int run = tmp[tid] - s;
    scanb[base+0] = run; run += v0;
    scanb[base+1] = run; run += v1;
    scanb[base+2] = run; run += v2;
    scanb[base+3] = run;
  }
  __syncthreads();
  for (int i = tid; i < NB; i += 256) {
    int h = hist[i];
    rbase[i] = h ? atomicAdd(&scur[i], h) : 0;
    lcur[i] = scanb[i];
  }
  __syncthreads();
  #pragma unroll
  for (int k = 0; k < BCH_BIN/256; ++k) {
    int e = e0 + k*256 + tid;
    if (e < E) {
      int s = src[e];
      int b = s >> 8;
      int p = atomicAdd(&lcur[b], 1);
      stage[p] = (unsigned)s;
    }
  }
  __syncthreads();
  for (int i = tid; i < nedge; i += 256) {
    unsigned sv = stage[i];
    int b = (int)(sv >> 8);
    // slot within run: i - scanb[b]
    sbuf[rbase[b] + (i - scanb[b])] = sv;
  }
}

// C4a: per-dst-bucket counting sort -> rp, din_is, col
__global__ __launch_bounds__(256) void finalize_dst_kernel(
    const unsigned* __restrict__ ebuf, const int* __restrict__ bbase,
    int* __restrict__ rp, float* __restrict__ din_is,
    int* __restrict__ col, int N) {
  __shared__ int lcnt[256];
  __shared__ int lrp[257];
  __shared__ int lcur[256];
  __shared__ int tmp[256];
  __shared__ int colbuf[BCAP];
  int b = blockIdx.x;
  int tid = threadIdx.x;
  int node0 = b << 8;
  int e0 = bbase[b], e1 = bbase[b+1];
  int ne = e1 - e0;
  lcnt[tid] = 0;
  __syncthreads();
  for (int i = tid; i < ne; i += 256)
    atomicAdd(&lcnt[ebuf[e0+i] >> 24], 1);
  __syncthreads();
  int c = lcnt[tid];
  tmp[tid] = c;
  __syncthreads();
  for (int off=1; off<256; off<<=1){
    int x = (tid >= off) ? tmp[tid-off] : 0;
    __syncthreads();
    tmp[tid] += x;
    __syncthreads();
  }
  lrp[tid] = tmp[tid] - c;
  lcur[tid] = tmp[tid] - c;
  if (tid == 255) lrp[256] = tmp[255];
  __syncthreads();
  int node = node0 + tid;
  if (node < N) {
    rp[node] = e0 + lrp[tid];
    int cc = c < 1 ? 1 : c;
    din_is[node] = rsqrtf((float)cc);
  }
  if (ne <= BCAP) {
    for (int i = tid; i < ne; i += 256) {
      unsigned ed = ebuf[e0+i];
      int p = atomicAdd(&lcur[ed >> 24], 1);
      colbuf[p] = (int)(ed & 0xFFFFFFu);
    }
    __syncthreads();
    for (int i = tid; i < ne; i += 256) col[e0+i] = colbuf[i];
  } else {
    for (int i = tid; i < ne; i += 256) {
      unsigned ed = ebuf[e0+i];
      int p = atomicAdd(&lcur[ed >> 24], 1);
      col[e0+p] = (int)(ed & 0xFFFFFFu);
    }
  }
}

// C4b: per-src-bucket counting histogram -> dout_is
__global__ __launch_bounds__(256) void finalize_src_kernel(
    const unsigned* __restrict__ sbuf, const int* __restrict__ sbase,
    float* __restrict__ dout_is, int N) {
  __shared__ int lcnt[256];
  int b = blockIdx.x;
  int tid = threadIdx.x;
  int node0 = b << 8;
  int e0 = sbase[b], e1 = sbase[b+1];
  lcnt[tid] = 0;
  __syncthreads();
  for (int i = tid; i < e1 - e0; i += 256)
    atomicAdd(&lcnt[sbuf[e0+i] & 255u], 1);
  __syncthreads();
  int node = node0 + tid;
  if (node < N) {
    int c = lcnt[tid]; if (c < 1) c = 1;
    dout_is[node] = rsqrtf((float)c);
  }
}

// ---------------- W -> transposed bf16 hi/lo: Wt[n][k], padded to npad rows ----------------
__global__ void wt_hilo_kernel(const float* __restrict__ W, unsigned short* __restrict__ Wthi,
                               unsigned short* __restrict__ Wtlo, int nreal, int npad) {
  int idx = blockIdx.x * blockDim.x + threadIdx.x;
  if (idx >= npad * 128) return;
  int n = idx >> 7;
  int k = idx & 127;
  float v = (n < nreal) ? W[k * nreal + n] : 0.f;
  unsigned short h = f2bf(v);
  float r = v - bf2f(h);
  Wthi[idx] = h;
  Wtlo[idx] = f2bf(r);
}

// ---------------- cast x (fp32 row) -> bf16 row pre-scaled by dout_is ----------------
__global__ void cast_scale_kernel(const float* __restrict__ x, const float* __restrict__ dout_is,
                                  unsigned* __restrict__ xb2, int n4) {
  int i = blockIdx.x * blockDim.x + threadIdx.x;
  if (i >= n4) return;
  float4 v = ((const float4*)x)[i];
  int row = i >> 5;
  float sc = dout_is[row];
  unsigned lo = (unsigned)f2bf(v.x * sc) | ((unsigned)f2bf(v.y * sc) << 16);
  unsigned hi = (unsigned)f2bf(v.z * sc) | ((unsigned)f2bf(v.w * sc) << 16);
  ((uint2*)xb2)[i] = make_uint2(lo, hi);
}

__device__ inline void acc8(float* a, uint4 v) {
  float2 f;
  f = bfp2f2(v.x); a[0]+=f.x; a[1]+=f.y;
  f = bfp2f2(v.y); a[2]+=f.x; a[3]+=f.y;
  f = bfp2f2(v.z); a[4]+=f.x; a[5]+=f.y;
  f = bfp2f2(v.w); a[6]+=f.x; a[7]+=f.y;
}

// ---------------- aggregation over bf16 rows (dout-prescaled), D=128, fp32 out ----------------
__global__ __launch_bounds__(256) void agg128_kernel(
    const uint4* __restrict__ hb4,
    const int* __restrict__ rp, const int* __restrict__ col,
    const float* __restrict__ din_is, float* __restrict__ out, int N) {
  int wave = (blockIdx.x * blockDim.x + threadIdx.x) >> 6;
  int lane = threadIdx.x & 63;
  int g = lane >> 4, j = lane & 15;
  int d = wave * 4 + g;
  if (d >= N) return;
  int s0 = rp[d], s1 = rp[d+1];
  float a[8] = {0.f,0.f,0.f,0.f,0.f,0.f,0.f,0.f};
  int e = s0;
  for (; e + 8 <= s1; e += 8) {
    int c0 = col[e],   c1 = col[e+1], c2 = col[e+2], c3 = col[e+3];
    int c4 = col[e+4], c5 = col[e+5], c6 = col[e+6], c7 = col[e+7];
    uint4 v0 = hb4[(size_t)c0*16 + j];
    uint4 v1 = hb4[(size_t)c1*16 + j];
    uint4 v2 = hb4[(size_t)c2*16 + j];
    uint4 v3 = hb4[(size_t)c3*16 + j];
    uint4 v4 = hb4[(size_t)c4*16 + j];
    uint4 v5 = hb4[(size_t)c5*16 + j];
    uint4 v6 = hb4[(size_t)c6*16 + j];
    uint4 v7 = hb4[(size_t)c7*16 + j];
    acc8(a, v0); acc8(a, v1); acc8(a, v2); acc8(a, v3);
    acc8(a, v4); acc8(a, v5); acc8(a, v6); acc8(a, v7);
  }
  for (; e + 4 <= s1; e += 4) {
    int c0 = col[e], c1 = col[e+1], c2 = col[e+2], c3 = col[e+3];
    uint4 v0 = hb4[(size_t)c0*16 + j];
    uint4 v1 = hb4[(size_t)c1*16 + j];
    uint4 v2 = hb4[(size_t)c2*16 + j];
    uint4 v3 = hb4[(size_t)c3*16 + j];
    acc8(a, v0); acc8(a, v1); acc8(a, v2); acc8(a, v3);
  }
  for (; e < s1; ++e) acc8(a, hb4[(size_t)col[e]*16 + j]);
  float di = din_is[d];
  float4* ob = (float4*)out + (size_t)d*32 + 2*j;
  ob[0] = make_float4(a[0]*di, a[1]*di, a[2]*di, a[3]*di);
  ob[1] = make_float4(a[4]*di, a[5]*di, a[6]*di, a[7]*di);
}

// ---------------- MFMA GEMM 128->128: A fp32 (hi/lo split in-register), +bias ----------------
__global__ __launch_bounds__(256) void gemm128_kernel(
    const float* __restrict__ A,
    const uint4* __restrict__ Bhi, const uint4* __restrict__ Blo,
    const float* __restrict__ bias, float* __restrict__ Out, int N) {
  int wave = threadIdx.x >> 6;
  int lane = threadIdx.x & 63;
  int quad = lane >> 4, j = lane & 15;
  int row0 = blockIdx.x * 64 + wave * 16;
  int row = row0 + j;
  int rl = row < N ? row : N - 1;
  floatx4 acc[8];
  #pragma unroll
  for (int ct = 0; ct < 8; ++ct) acc[ct] = (floatx4){0.f,0.f,0.f,0.f};
  #pragma unroll
  for (int kc = 0; kc < 4; ++kc) {
    const float* ap = A + (size_t)rl*128 + kc*32 + quad*8;
    float4 f0 = *(const float4*)(ap);
    float4 f1 = *(const float4*)(ap + 4);
    uint4 H, L;
    hilo2(f0.x, f0.y, H.x, L.x);
    hilo2(f0.z, f0.w, H.y, L.y);
    hilo2(f1.x, f1.y, H.z, L.z);
    hilo2(f1.z, f1.w, H.w, L.w);
    bf16x8 ah = asbf(H), al = asbf(L);
    #pragma unroll
    for (int ct = 0; ct < 8; ++ct) {
      int nr = ct*16 + j;
      uint4 bh = Bhi[nr*16 + kc*4 + quad];
      uint4 bl = Blo[nr*16 + kc*4 + quad];
      acc[ct] = __builtin_amdgcn_mfma_f32_16x16x32_bf16(ah, asbf(bh), acc[ct], 0, 0, 0);
      acc[ct] = __builtin_amdgcn_mfma_f32_16x16x32_bf16(ah, asbf(bl), acc[ct], 0, 0, 0);
      acc[ct] = __builtin_amdgcn_mfma_f32_16x16x32_bf16(al, asbf(bh), acc[ct], 0, 0, 0);
    }
  }
  #pragma unroll
  for (int ct = 0; ct < 8; ++ct) {
    int colc = ct*16 + j;
    float bs = bias[colc];
    #pragma unroll
    for (int r = 0; r < 4; ++r) {
      int grow = row0 + quad*4 + r;
      if (grow < N) Out[(size_t)grow*128 + colc] = acc[ct][r] + bs;
    }
  }
}

// ---------------- FUSED: BN-apply + ReLU + MFMA GEMM (128 -> 40, bf16 out) ----------------
__global__ __launch_bounds__(256) void bn_gemm40_kernel(
    const float* __restrict__ A,
    const float* __restrict__ colA, const float* __restrict__ colB,
    const uint4* __restrict__ Bhi, const uint4* __restrict__ Blo,
    const float* __restrict__ rowscale,
    unsigned short* __restrict__ OutB, int N) {
  int wave = threadIdx.x >> 6;
  int lane = threadIdx.x & 63;
  int quad = lane >> 4, j = lane & 15;
  int row0 = blockIdx.x * 64 + wave * 16;
  int row = row0 + j;
  int rl = row < N ? row : N - 1;
  floatx4 acc[3];
  #pragma unroll
  for (int ct = 0; ct < 3; ++ct) acc[ct] = (floatx4){0.f,0.f,0.f,0.f};
  #pragma unroll
  for (int kc = 0; kc < 4; ++kc) {
    const float* ap = A + (size_t)rl*128 + kc*32 + quad*8;
    float4 f0 = *(const float4*)(ap);
    float4 f1 = *(const float4*)(ap + 4);
    const float* ca = colA + kc*32 + quad*8;
    const float* cb = colB + kc*32 + quad*8;
    float4 a0 = *(const float4*)(ca), a1 = *(const float4*)(ca + 4);
    float4 b0 = *(const float4*)(cb), b1 = *(const float4*)(cb + 4);
    float y0 = fmaxf(f0.x*a0.x + b0.x, 0.f);
    float y1 = fmaxf(f0.y*a0.y + b0.y, 0.f);
    float y2 = fmaxf(f0.z*a0.z + b0.z, 0.f);
    float y3 = fmaxf(f0.w*a0.w + b0.w, 0.f);
    float y4 = fmaxf(f1.x*a1.x + b1.x, 0.f);
    float y5 = fmaxf(f1.y*a1.y + b1.y, 0.f);
    float y6 = fmaxf(f1.z*a1.z + b1.z, 0.f);
    float y7 = fmaxf(f1.w*a1.w + b1.w, 0.f);
    uint4 H, L;
    hilo2(y0, y1, H.x, L.x);
    hilo2(y2, y3, H.y, L.y);
    hilo2(y4, y5, H.z, L.z);
    hilo2(y6, y7, H.w, L.w);
    bf16x8 ah = asbf(H), al = asbf(L);
    #pragma unroll
    for (int ct = 0; ct < 3; ++ct) {
      int nr = ct*16 + j;
      uint4 bh = Bhi[nr*16 + kc*4 + quad];
      uint4 bl = Blo[nr*16 + kc*4 + quad];
      acc[ct] = __builtin_amdgcn_mfma_f32_16x16x32_bf16(ah, asbf(bh), acc[ct], 0, 0, 0);
      acc[ct] = __builtin_amdgcn_mfma_f32_16x16x32_bf16(ah, asbf(bl), acc[ct], 0, 0, 0);
      acc[ct] = __builtin_amdgcn_mfma_f32_16x16x32_bf16(al, asbf(bh), acc[ct], 0, 0, 0);
    }
  }
  #pragma unroll
  for (int r = 0; r < 4; ++r) {
    int grow = row0 + quad*4 + r;
    if (grow < N) {
      float sc = rowscale[grow];
      #pragma unroll
      for (int ct = 0; ct < 3; ++ct) {
        int colc = ct*16 + j;
        if (colc < 40) OutB[(size_t)grow*40 + colc] = f2bf(acc[ct][r] * sc);
      }
    }
  }
}

// ---------------- BatchNorm stats ----------------
__global__ void bn_reduce_kernel(const float* __restrict__ h, float* __restrict__ gsum,
                                 float* __restrict__ gsumsq, int N, int rpb) {
  int f = threadIdx.x;
  int r0 = blockIdx.x * rpb;
  int r1 = r0 + rpb; if (r1 > N) r1 = N;
  float s = 0.f, ss = 0.f;
  for (int r = r0; r < r1; ++r) {
    float v = h[(size_t)r*128 + f];
    s += v; ss += v*v;
  }
  atomicAdd(&gsum[f], s);
  atomicAdd(&gsumsq[f], ss);
}

__global__ void bn_params_kernel(const float* __restrict__ gsum, const float* __restrict__ gsumsq,
                                 const float* __restrict__ g, const float* __restrict__ be,
                                 float* __restrict__ colA, float* __restrict__ colB, float invN) {
  int f = threadIdx.x;
  float mu  = gsum[f] * invN;
  float var = gsumsq[f] * invN - mu*mu;
  if (var < 0.f) var = 0.f;
  float rs = rsqrtf(var + 1e-5f);
  float a = g[f] * rs;
  colA[f] = a;
  colB[f] = be[f] - mu*a;
}

__global__ void bn_apply_bf16_kernel(const float* __restrict__ raw, const float* __restrict__ colA,
                                     const float* __restrict__ colB, const float* __restrict__ dout_is,
                                     unsigned* __restrict__ outb, int n4) {
  int i = blockIdx.x * blockDim.x + threadIdx.x;
  if (i >= n4) return;
  float4 v = ((const float4*)raw)[i];
  int c4 = i & 31;
  int row = i >> 5;
  float sc = dout_is[row];
  float4 a = ((const float4*)colA)[c4];
  float4 b = ((const float4*)colB)[c4];
  float x0 = fmaxf(v.x*a.x + b.x, 0.f) * sc;
  float x1 = fmaxf(v.y*a.y + b.y, 0.f) * sc;
  float x2 = fmaxf(v.z*a.z + b.z, 0.f) * sc;
  float x3 = fmaxf(v.w*a.w + b.w, 0.f) * sc;
  unsigned lo = (unsigned)f2bf(x0) | ((unsigned)f2bf(x1) << 16);
  unsigned hi = (unsigned)f2bf(x2) | ((unsigned)f2bf(x3) << 16);
  ((uint2*)outb)[i] = make_uint2(lo, hi);
}

// ---------------- layer 3: aggregate 40-dim bf16 (pre-scaled) + bias + log_softmax ----------------
__global__ __launch_bounds__(256) void final_kernel(
    const unsigned* __restrict__ tb,
    const int* __restrict__ rp, const int* __restrict__ col,
    const float* __restrict__ din_is, const float* __restrict__ b3,
    float* __restrict__ out, int N) {
  int wave = (blockIdx.x * blockDim.x + threadIdx.x) >> 6;
  int g = (threadIdx.x >> 5) & 1;
  int j = threadIdx.x & 31;
  int d = wave * 2 + g;
  if (d >= N) return;
  bool act = (j < 20);
  int s0 = rp[d], s1 = rp[d+1];
  float a0 = 0.f, a1 = 0.f;
  int e = s0;
  for (; e + 8 <= s1; e += 8) {
    int c0 = col[e],   c1 = col[e+1], c2 = col[e+2], c3 = col[e+3];
    int c4 = col[e+4], c5 = col[e+5], c6 = col[e+6], c7 = col[e+7];
    unsigned u0 = act ? tb[(size_t)c0*20 + j] : 0u;
    unsigned u1 = act ? tb[(size_t)c1*20 + j] : 0u;
    unsigned u2 = act ? tb[(size_t)c2*20 + j] : 0u;
    unsigned u3 = act ? tb[(size_t)c3*20 + j] : 0u;
    unsigned u4 = act ? tb[(size_t)c4*20 + j] : 0u;
    unsigned u5 = act ? tb[(size_t)c5*20 + j] : 0u;
    unsigned u6 = act ? tb[(size_t)c6*20 + j] : 0u;
    unsigned u7 = act ? tb[(size_t)c7*20 + j] : 0u;
    float2 f0 = bfp2f2(u0), f1 = bfp2f2(u1), f2 = bfp2f2(u2), f3 = bfp2f2(u3);
    float2 f4 = bfp2f2(u4), f5 = bfp2f2(u5), f6 = bfp2f2(u6), f7 = bfp2f2(u7);
    a0 += ((f0.x + f1.x) + (f2.x + f3.x)) + ((f4.x + f5.x) + (f6.x + f7.x));
    a1 += ((f0.y + f1.y) + (f2.y + f3.y)) + ((f4.y + f5.y) + (f6.y + f7.y));
  }
  for (; e + 4 <= s1; e += 4) {
    int c0 = col[e], c1 = col[e+1], c2 = col[e+2], c3 = col[e+3];
    unsigned u0 = act ? tb[(size_t)c0*20 + j] : 0u;
    unsigned u1 = act ? tb[(size_t)c1*20 + j] : 0u;
    unsigned u2 = act ? tb[(size_t)c2*20 + j] : 0u;
    unsigned u3 = act ? tb[(size_t)c3*20 + j] : 0u;
    float2 f0 = bfp2f2(u0), f1 = bfp2f2(u1), f2 = bfp2f2(u2), f3 = bfp2f2(u3);
    a0 += (f0.x + f1.x) + (f2.x + f3.x);
    a1 += (f0.y + f1.y) + (f2.y + f3.y);
  }
  for (; e < s1; ++e) {
    unsigned u = act ? tb[(size_t)col[e]*20 + j] : 0u;
    float2 f = bfp2f2(u);
    a0 += f.x; a1 += f.y;
  }
  float di = din_is[d];
  float z0 = act ? di*a0 + b3[2*j]   : -1e30f;
  float z1 = act ? di*a1 + b3[2*j+1] : -1e30f;
  float m = fmaxf(z0, z1);
  #pragma unroll
  for (int off=16; off>0; off>>=1) m = fmaxf(m, __shfl_xor(m, off, 32));
  float s = act ? (expf(z0-m) + expf(z1-m)) : 0.f;
  #pragma unroll
  for (int off=16; off>0; off>>=1) s += __shfl_xor(s, off, 32);
  float lg = logf(s);
  if (act) {
    float2 o = make_float2(z0 - m - lg, z1 - m - lg);
    ((float2*)(out + (size_t)d*40))[j] = o;
  }
}

// ---------------- host ----------------
extern "C" void kernel_launch(void* const* d_in, const int* in_sizes, int n_in,
                              void* d_out, int out_size, void* d_ws, size_t ws_size,
                              hipStream_t stream) {
  const float* x   = (const float*)d_in[0];
  const int*   src = (const int*)d_in[1];
  const int*   dst = (const int*)d_in[2];
  const float* W1  = (const float*)d_in[3];
  const float* b1  = (const float*)d_in[4];
  const float* g1  = (const float*)d_in[5];
  const float* be1 = (const float*)d_in[6];
  const float* W2  = (const float*)d_in[7];
  const float* b2  = (const float*)d_in[8];
  const float* g2  = (const float*)d_in[9];
  const float* be2 = (const float*)d_in[10];
  const float* W3  = (const float*)d_in[11];
  const float* b3  = (const float*)d_in[12];
  const int E = in_sizes[1];
  const int D = in_sizes[4];     // 128
  const int N = in_sizes[0] / D; // 100000
  float* out = (float*)d_out;

  char* p = (char*)d_ws;
  auto alloc = [&](size_t bytes) { char* q = p; p += (bytes + 255) & ~(size_t)255; return q; };
  int* rp        = (int*)alloc((size_t)(N+1)*4);
  float* din_is  = (float*)alloc((size_t)N*4);
  float* dout_is = (float*)alloc((size_t)N*4);
  float* gsum    = (float*)alloc((size_t)D*4);
  float* gsumsq  = (float*)alloc((size_t)D*4);
  float* colAp   = (float*)alloc((size_t)D*4);
  float* colBp   = (float*)alloc((size_t)D*4);
  int* bcnt      = (int*)alloc((size_t)MAXNB*4);
  int* bbase     = (int*)alloc((size_t)(MAXNB+1)*4);
  int* bcur      = (int*)alloc((size_t)MAXNB*4);
  int* scnt      = (int*)alloc((size_t)MAXNB*4);
  int* sbase     = (int*)alloc((size_t)(MAXNB+1)*4);
  int* scur      = (int*)alloc((size_t)MAXNB*4);
  unsigned short* Wt1hi = (unsigned short*)alloc(128*128*2);
  unsigned short* Wt1lo = (unsigned short*)alloc(128*128*2);
  unsigned short* Wt2hi = (unsigned short*)alloc(128*128*2);
  unsigned short* Wt2lo = (unsigned short*)alloc(128*128*2);
  unsigned short* Wt3hi = (unsigned short*)alloc(48*128*2);
  unsigned short* Wt3lo = (unsigned short*)alloc(48*128*2);
  int*   col     = (int*)alloc((size_t)E*4);
  float* bufA    = (float*)alloc((size_t)N*D*4);      // GEMM output (fp32)
  float* bufB    = (float*)alloc((size_t)N*D*4);      // agg output (fp32)
  unsigned* bf16buf = (unsigned*)alloc((size_t)N*D*2);
  // aliases: CSR build finishes before bufA/bufB first writes
  unsigned* ebuf = (unsigned*)bufA;   // E uints (packed dst-low|src)
  unsigned* sbuf = (unsigned*)bufB;   // E uints (src)

  const int NB = (N + 255) >> 8;
  int cntB = (E + BCH_CNT - 1)/BCH_CNT;
  int binB = (E + BCH_BIN - 1)/BCH_BIN;

  hipMemsetAsync(bcnt, 0, (size_t)MAXNB*4, stream);
  hipMemsetAsync(scnt, 0, (size_t)MAXNB*4, stream);
  wt_hilo_kernel<<<(128*128+255)/256, 256, 0, stream>>>(W1, Wt1hi, Wt1lo, 128, 128);
  wt_hilo_kernel<<<(128*128+255)/256, 256, 0, stream>>>(W2, Wt2hi, Wt2lo, 128, 128);
  wt_hilo_kernel<<<(48*128+255)/256, 256, 0, stream>>>(W3, Wt3hi, Wt3lo, 40, 48);
  count2_kernel<<<cntB, 256, 0, stream>>>(src, dst, bcnt, scnt, E, NB);
  scan2_kernel<<<1, 256, 0, stream>>>(bcnt, bbase, bcur, scnt, sbase, scur, rp, NB, N, E);
  bin_dst_kernel<<<binB, 256, 0, stream>>>(src, dst, bcur, ebuf, E, NB);
  bin_src_kernel<<<binB, 256, 0, stream>>>(src, scur, sbuf, E, NB);
  finalize_dst_kernel<<<NB, 256, 0, stream>>>(ebuf, bbase, rp, din_is, col, N);
  finalize_src_kernel<<<NB, 256, 0, stream>>>(sbuf, sbase, dout_is, N);

  int aggb = ((N + 3)/4*64 + 255)/256;    // 4 dst per wave
  int finb = ((N + 1)/2*64 + 255)/256;    // 2 dst per wave
  int gemb = (N + 63)/64;                 // 64 rows per block
  int rpb  = (N + 511)/512;
  int nel4 = (N*D)/4;

  // layer 1
  cast_scale_kernel<<<(nel4+255)/256, 256, 0, stream>>>(x, dout_is, bf16buf, nel4);
  agg128_kernel<<<aggb, 256, 0, stream>>>((const uint4*)bf16buf, rp, col, din_is, bufB, N);
  gemm128_kernel<<<gemb, 256, 0, stream>>>(bufB, (const uint4*)Wt1hi, (const uint4*)Wt1lo, b1, bufA, N);
  hipMemsetAsync(gsum, 0, (size_t)D*4, stream);
  hipMemsetAsync(gsumsq, 0, (size_t)D*4, stream);
  bn_reduce_kernel<<<512, 128, 0, stream>>>(bufA, gsum, gsumsq, N, rpb);
  bn_params_kernel<<<1, 128, 0, stream>>>(gsum, gsumsq, g1, be1, colAp, colBp, 1.0f/(float)N);
  bn_apply_bf16_kernel<<<(nel4+255)/256, 256, 0, stream>>>(bufA, colAp, colBp, dout_is, bf16buf, nel4);

  // layer 2
  agg128_kernel<<<aggb, 256, 0, stream>>>((const uint4*)bf16buf, rp, col, din_is, bufB, N);
  gemm128_kernel<<<gemb, 256, 0, stream>>>(bufB, (const uint4*)Wt2hi, (const uint4*)Wt2lo, b2, bufA, N);
  hipMemsetAsync(gsum, 0, (size_t)D*4, stream);
  hipMemsetAsync(gsumsq, 0, (size_t)D*4, stream);
  bn_reduce_kernel<<<512, 128, 0, stream>>>(bufA, gsum, gsumsq, N, rpb);
  bn_params_kernel<<<1, 128, 0, stream>>>(gsum, gsumsq, g2, be2, colAp, colBp, 1.0f/(float)N);

  // layer 3: fused BN + GEMM to 40 dims (bf16 out pre-scaled by dout), then agg + softmax
  bn_gemm40_kernel<<<gemb, 256, 0, stream>>>(bufA, colAp, colBp,
                                             (const uint4*)Wt3hi, (const uint4*)Wt3lo,
                                             dout_is, (unsigned short*)bf16buf, N);
  final_kernel<<<finb, 256, 0, stream>>>((const unsigned*)bf16buf, rp, col, din_is, b3, out, N);
}

// Round 10
// 677.832 us; speedup vs baseline: 1.1250x; 1.0512x over previous
//
#include <hip/hip_runtime.h>
#include <math.h>

#define MAXNB 1024    // max buckets (N <= 262144 with 256 nodes/bucket)
#define BCH_CNT 2048  // edges per block in count kernel
#define BCH_BIN 2048  // edges per block in bin kernels
#define BCAP  16384   // per-bucket edge capacity in finalize (mean 4096)

typedef __attribute__((ext_vector_type(8))) __bf16 bf16x8;
typedef __attribute__((ext_vector_type(4))) float floatx4;

__device__ inline bf16x8 asbf(uint4 u) {
  union { uint4 u; bf16x8 b; } c; c.u = u; return c.b;
}

// ---------- bf16 helpers ----------
__device__ inline unsigned short f2bf(float f) {
  union { float f; unsigned u; } v; v.f = f;
  unsigned r = v.u + 0x7fffu + ((v.u >> 16) & 1u);   // round-to-nearest-even
  return (unsigned short)(r >> 16);
}
__device__ inline float bf2f(unsigned short u) {
  union { unsigned u; float f; } v; v.u = ((unsigned)u) << 16;
  return v.f;
}
__device__ inline float2 bfp2f2(unsigned u) {       // packed bf16x2 -> float2
  union { unsigned u; float f; } a, b;
  a.u = u << 16;
  b.u = u & 0xffff0000u;
  float2 r; r.x = a.f; r.y = b.f; return r;
}
// split v into hi=bf16(v), lo=bf16(v-hi); packed pair for 2 values
__device__ inline void hilo2(float v0, float v1, unsigned& h, unsigned& l) {
  unsigned short h0 = f2bf(v0); float r0 = v0 - bf2f(h0);
  unsigned short h1 = f2bf(v1); float r1 = v1 - bf2f(h1);
  h = (unsigned)h0 | ((unsigned)h1 << 16);
  l = (unsigned)f2bf(r0) | ((unsigned)f2bf(r1) << 16);
}

// ---------------- CSR build: bucketed sorts for dst (CSR) and src (out-degree) ----------------
__global__ __launch_bounds__(256) void count2_kernel(
    const int* __restrict__ src, const int* __restrict__ dst,
    int* __restrict__ bcnt, int* __restrict__ scnt, int E, int NB) {
  __shared__ int histd[MAXNB];
  __shared__ int hists[MAXNB];
  int tid = threadIdx.x;
  for (int i = tid; i < MAXNB; i += 256) { histd[i] = 0; hists[i] = 0; }
  __syncthreads();
  int e0 = blockIdx.x * BCH_CNT;
  #pragma unroll
  for (int k = 0; k < BCH_CNT/256; ++k) {
    int e = e0 + k*256 + tid;
    if (e < E) {
      atomicAdd(&histd[dst[e] >> 8], 1);
      atomicAdd(&hists[src[e] >> 8], 1);
    }
  }
  __syncthreads();
  for (int i = tid; i < NB; i += 256) {
    if (histd[i]) atomicAdd(&bcnt[i], histd[i]);
    if (hists[i]) atomicAdd(&scnt[i], hists[i]);
  }
}

__global__ __launch_bounds__(256) void scan2_kernel(
    const int* __restrict__ bcnt, int* __restrict__ bbase, int* __restrict__ bcur,
    const int* __restrict__ scnt, int* __restrict__ sbase, int* __restrict__ scur,
    int* __restrict__ rp, int NB, int N, int E) {
  __shared__ int sh[256];
  int t = threadIdx.x;
  for (int pass = 0; pass < 2; ++pass) {
    const int* cnt = pass ? scnt : bcnt;
    int* base_ = pass ? sbase : bbase;
    int* cur_  = pass ? scur  : bcur;
    int base = t * 4;
    int v0 = (base+0 < NB) ? cnt[base+0] : 0;
    int v1 = (base+1 < NB) ? cnt[base+1] : 0;
    int v2 = (base+2 < NB) ? cnt[base+2] : 0;
    int v3 = (base+3 < NB) ? cnt[base+3] : 0;
    int s = v0+v1+v2+v3;
    sh[t] = s;
    __syncthreads();
    for (int off=1; off<256; off<<=1){
      int x = (t >= off) ? sh[t-off] : 0;
      __syncthreads();
      sh[t] += x;
      __syncthreads();
    }
    int run = sh[t] - s;
    if (base+0 <= NB) { base_[base+0] = run; if (base+0 < NB) cur_[base+0] = run; } run += v0;
    if (base+1 <= NB) { base_[base+1] = run; if (base+1 < NB) cur_[base+1] = run; } run += v1;
    if (base+2 <= NB) { base_[base+2] = run; if (base+2 < NB) cur_[base+2] = run; } run += v2;
    if (base+3 <= NB) { base_[base+3] = run; if (base+3 < NB) cur_[base+3] = run; }
    __syncthreads();
  }
  if (t == 0) rp[N] = E;
}

// C3a: bin by dst bucket; payload packed (dst&255)<<24 | src  (needs N < 2^24)
__global__ __launch_bounds__(256) void bin_dst_kernel(
    const int* __restrict__ src, const int* __restrict__ dst,
    int* __restrict__ bcur, unsigned* __restrict__ ebuf, int E, int NB) {
  __shared__ int hist[MAXNB];
  __shared__ int scanb[MAXNB];
  __shared__ int rbase[MAXNB];
  __shared__ int lcur[MAXNB];
  __shared__ int tmp[256];
  __shared__ unsigned stage[BCH_BIN];
  int tid = threadIdx.x;
  int e0 = blockIdx.x * BCH_BIN;
  int nedge = E - e0; if (nedge > BCH_BIN) nedge = BCH_BIN; if (nedge < 0) nedge = 0;
  for (int i = tid; i < MAXNB; i += 256) hist[i] = 0;
  __syncthreads();
  #pragma unroll
  for (int k = 0; k < BCH_BIN/256; ++k) {
    int e = e0 + k*256 + tid;
    if (e < E) atomicAdd(&hist[dst[e] >> 8], 1);
  }
  __syncthreads();
  {
    int base = tid * 4;
    int v0 = hist[base+0], v1 = hist[base+1], v2 = hist[base+2], v3 = hist[base+3];
    int s = v0+v1+v2+v3;
    tmp[tid] = s;
    __syncthreads();
    for (int off=1; off<256; off<<=1){
      int x = (tid >= off) ? tmp[tid-off] : 0;
      __syncthreads();
      tmp[tid] += x;
      __syncthreads();
    }
    int run = tmp[tid] - s;
    scanb[base+0] = run; run += v0;
    scanb[base+1] = run; run += v1;
    scanb[base+2] = run; run += v2;
    scanb[base+3] = run;
  }
  __syncthreads();
  for (int i = tid; i < NB; i += 256) {
    int h = hist[i];
    rbase[i] = h ? atomicAdd(&bcur[i], h) : 0;
    lcur[i] = scanb[i];
  }
  __syncthreads();
  #pragma unroll
  for (int k = 0; k < BCH_BIN/256; ++k) {
    int e = e0 + k*256 + tid;
    if (e < E) {
      int d = dst[e];
      int b = d >> 8;
      int p = atomicAdd(&lcur[b], 1);
      stage[p] = ((unsigned)(d & 255) << 24) | (unsigned)src[e];
    }
  }
  __syncthreads();
  for (int i = tid; i < nedge; i += 256) {
    unsigned ed = stage[i];
    int lo = 0, hi = NB - 1;
    while (lo < hi) {
      int mid = (lo + hi + 1) >> 1;
      if (scanb[mid] <= i) lo = mid; else hi = mid - 1;
    }
    ebuf[rbase[lo] + (i - scanb[lo])] = ed;
  }
}

// C3b: bin src values by src bucket (payload = src)
__global__ __launch_bounds__(256) void bin_src_kernel(
    const int* __restrict__ src,
    int* __restrict__ scur, unsigned* __restrict__ sbuf, int E, int NB) {
  __shared__ int hist[MAXNB];
  __shared__ int scanb[MAXNB];
  __shared__ int rbase[MAXNB];
  __shared__ int lcur[MAXNB];
  __shared__ int tmp[256];
  __shared__ unsigned stage[BCH_BIN];
  int tid = threadIdx.x;
  int e0 = blockIdx.x * BCH_BIN;
  int nedge = E - e0; if (nedge > BCH_BIN) nedge = BCH_BIN; if (nedge < 0) nedge = 0;
  for (int i = tid; i < MAXNB; i += 256) hist[i] = 0;
  __syncthreads();
  #pragma unroll
  for (int k = 0; k < BCH_BIN/256; ++k) {
    int e = e0 + k*256 + tid;
    if (e < E) atomicAdd(&hist[src[e] >> 8], 1);
  }
  __syncthreads();
  {
    int base = tid * 4;
    int v0 = hist[base+0], v1 = hist[base+1], v2 = hist[base+2], v3 = hist[base+3];
    int s = v0+v1+v2+v3;
    tmp[tid] = s;
    __syncthreads();
    for (int off=1; off<256; off<<=1){
      int x = (tid >= off) ? tmp[tid-off] : 0;
      __syncthreads();
      tmp[tid] += x;
      __syncthreads();
    }
    int run = tmp[tid] - s;
    scanb[base+0] = run; run += v0;
    scanb[base+1] = run; run += v1;
    scanb[base+2] = run; run += v2;
    scanb[base+3] = run;
  }
  __syncthreads();
  for (int i = tid; i < NB; i += 256) {
    int h = hist[i];
    rbase[i] = h ? atomicAdd(&scur[i], h) : 0;
    lcur[i] = scanb[i];
  }
  __syncthreads();
  #pragma unroll
  for (int k = 0; k < BCH_BIN/256; ++k) {
    int e = e0 + k*256 + tid;
    if (e < E) {
      int s = src[e];
      int b = s >> 8;
      int p = atomicAdd(&lcur[b], 1);
      stage[p] = (unsigned)s;
    }
  }
  __syncthreads();
  for (int i = tid; i < nedge; i += 256) {
    unsigned sv = stage[i];
    int b = (int)(sv >> 8);
    sbuf[rbase[b] + (i - scanb[b])] = sv;
  }
}

// C4a: per-dst-bucket counting sort -> rp, din_is, col
__global__ __launch_bounds__(256) void finalize_dst_kernel(
    const unsigned* __restrict__ ebuf, const int* __restrict__ bbase,
    int* __restrict__ rp, float* __restrict__ din_is,
    int* __restrict__ col, int N) {
  __shared__ int lcnt[256];
  __shared__ int lrp[257];
  __shared__ int lcur[256];
  __shared__ int tmp[256];
  __shared__ int colbuf[BCAP];
  int b = blockIdx.x;
  int tid = threadIdx.x;
  int node0 = b << 8;
  int e0 = bbase[b], e1 = bbase[b+1];
  int ne = e1 - e0;
  lcnt[tid] = 0;
  __syncthreads();
  for (int i = tid; i < ne; i += 256)
    atomicAdd(&lcnt[ebuf[e0+i] >> 24], 1);
  __syncthreads();
  int c = lcnt[tid];
  tmp[tid] = c;
  __syncthreads();
  for (int off=1; off<256; off<<=1){
    int x = (tid >= off) ? tmp[tid-off] : 0;
    __syncthreads();
    tmp[tid] += x;
    __syncthreads();
  }
  lrp[tid] = tmp[tid] - c;
  lcur[tid] = tmp[tid] - c;
  if (tid == 255) lrp[256] = tmp[255];
  __syncthreads();
  int node = node0 + tid;
  if (node < N) {
    rp[node] = e0 + lrp[tid];
    int cc = c < 1 ? 1 : c;
    din_is[node] = rsqrtf((float)cc);
  }
  if (ne <= BCAP) {
    for (int i = tid; i < ne; i += 256) {
      unsigned ed = ebuf[e0+i];
      int p = atomicAdd(&lcur[ed >> 24], 1);
      colbuf[p] = (int)(ed & 0xFFFFFFu);
    }
    __syncthreads();
    for (int i = tid; i < ne; i += 256) col[e0+i] = colbuf[i];
  } else {
    for (int i = tid; i < ne; i += 256) {
      unsigned ed = ebuf[e0+i];
      int p = atomicAdd(&lcur[ed >> 24], 1);
      col[e0+p] = (int)(ed & 0xFFFFFFu);
    }
  }
}

// C4b: per-src-bucket counting histogram -> dout_is
__global__ __launch_bounds__(256) void finalize_src_kernel(
    const unsigned* __restrict__ sbuf, const int* __restrict__ sbase,
    float* __restrict__ dout_is, int N) {
  __shared__ int lcnt[256];
  int b = blockIdx.x;
  int tid = threadIdx.x;
  int node0 = b << 8;
  int e0 = sbase[b], e1 = sbase[b+1];
  lcnt[tid] = 0;
  __syncthreads();
  for (int i = tid; i < e1 - e0; i += 256)
    atomicAdd(&lcnt[sbuf[e0+i] & 255u], 1);
  __syncthreads();
  int node = node0 + tid;
  if (node < N) {
    int c = lcnt[tid]; if (c < 1) c = 1;
    dout_is[node] = rsqrtf((float)c);
  }
}

// ---------------- W -> transposed bf16 hi/lo: Wt[n][k], padded to npad rows ----------------
__global__ void wt_hilo_kernel(const float* __restrict__ W, unsigned short* __restrict__ Wthi,
                               unsigned short* __restrict__ Wtlo, int nreal, int npad) {
  int idx = blockIdx.x * blockDim.x + threadIdx.x;
  if (idx >= npad * 128) return;
  int n = idx >> 7;
  int k = idx & 127;
  float v = (n < nreal) ? W[k * nreal + n] : 0.f;
  unsigned short h = f2bf(v);
  float r = v - bf2f(h);
  Wthi[idx] = h;
  Wtlo[idx] = f2bf(r);
}

// ---------------- cast x (fp32 row) -> bf16 row pre-scaled by dout_is ----------------
__global__ void cast_scale_kernel(const float* __restrict__ x, const float* __restrict__ dout_is,
                                  unsigned* __restrict__ xb2, int n4) {
  int i = blockIdx.x * blockDim.x + threadIdx.x;
  if (i >= n4) return;
  float4 v = ((const float4*)x)[i];
  int row = i >> 5;
  float sc = dout_is[row];
  unsigned lo = (unsigned)f2bf(v.x * sc) | ((unsigned)f2bf(v.y * sc) << 16);
  unsigned hi = (unsigned)f2bf(v.z * sc) | ((unsigned)f2bf(v.w * sc) << 16);
  ((uint2*)xb2)[i] = make_uint2(lo, hi);
}

__device__ inline void acc8(float* a, uint4 v) {
  float2 f;
  f = bfp2f2(v.x); a[0]+=f.x; a[1]+=f.y;
  f = bfp2f2(v.y); a[2]+=f.x; a[3]+=f.y;
  f = bfp2f2(v.z); a[4]+=f.x; a[5]+=f.y;
  f = bfp2f2(v.w); a[6]+=f.x; a[7]+=f.y;
}

// ---------------- aggregation over bf16 rows (dout-prescaled), D=128, fp32 out ----------------
__global__ __launch_bounds__(256) void agg128_kernel(
    const uint4* __restrict__ hb4,
    const int* __restrict__ rp, const int* __restrict__ col,
    const float* __restrict__ din_is, float* __restrict__ out, int N) {
  int wave = (blockIdx.x * blockDim.x + threadIdx.x) >> 6;
  int lane = threadIdx.x & 63;
  int g = lane >> 4, j = lane & 15;
  int d = wave * 4 + g;
  if (d >= N) return;
  int s0 = rp[d], s1 = rp[d+1];
  float a[8] = {0.f,0.f,0.f,0.f,0.f,0.f,0.f,0.f};
  int e = s0;
  for (; e + 8 <= s1; e += 8) {
    int c0 = col[e],   c1 = col[e+1], c2 = col[e+2], c3 = col[e+3];
    int c4 = col[e+4], c5 = col[e+5], c6 = col[e+6], c7 = col[e+7];
    uint4 v0 = hb4[(size_t)c0*16 + j];
    uint4 v1 = hb4[(size_t)c1*16 + j];
    uint4 v2 = hb4[(size_t)c2*16 + j];
    uint4 v3 = hb4[(size_t)c3*16 + j];
    uint4 v4 = hb4[(size_t)c4*16 + j];
    uint4 v5 = hb4[(size_t)c5*16 + j];
    uint4 v6 = hb4[(size_t)c6*16 + j];
    uint4 v7 = hb4[(size_t)c7*16 + j];
    acc8(a, v0); acc8(a, v1); acc8(a, v2); acc8(a, v3);
    acc8(a, v4); acc8(a, v5); acc8(a, v6); acc8(a, v7);
  }
  for (; e + 4 <= s1; e += 4) {
    int c0 = col[e], c1 = col[e+1], c2 = col[e+2], c3 = col[e+3];
    uint4 v0 = hb4[(size_t)c0*16 + j];
    uint4 v1 = hb4[(size_t)c1*16 + j];
    uint4 v2 = hb4[(size_t)c2*16 + j];
    uint4 v3 = hb4[(size_t)c3*16 + j];
    acc8(a, v0); acc8(a, v1); acc8(a, v2); acc8(a, v3);
  }
  for (; e < s1; ++e) acc8(a, hb4[(size_t)col[e]*16 + j]);
  float di = din_is[d];
  float4* ob = (float4*)out + (size_t)d*32 + 2*j;
  ob[0] = make_float4(a[0]*di, a[1]*di, a[2]*di, a[3]*di);
  ob[1] = make_float4(a[4]*di, a[5]*di, a[6]*di, a[7]*di);
}

// ---------------- MFMA GEMM 128->128 + fused BN stats ----------------
// 2-tile grid-stride pipeline: prefetch next tile's A while computing current.
// Epilogue accumulates per-column sum/sumsq -> conflict-free per-block partials.
__global__ __launch_bounds__(256) void gemm128_stats_kernel(
    const float* __restrict__ A,
    const uint4* __restrict__ Bhi, const uint4* __restrict__ Blo,
    const float* __restrict__ bias, float* __restrict__ Out,
    float* __restrict__ Ps, float* __restrict__ Pss, int N, int ntiles) {
  __shared__ float sblk[4][128];
  __shared__ float ssblk[4][128];
  int wave = threadIdx.x >> 6;
  int lane = threadIdx.x & 63;
  int quad = lane >> 4, j = lane & 15;
  float st[8], sst[8];
  #pragma unroll
  for (int ct = 0; ct < 8; ++ct) { st[ct] = 0.f; sst[ct] = 0.f; }

  int tile = blockIdx.x;
  float4 cur[8];
  if (tile < ntiles) {
    int row = tile * 64 + wave * 16 + j;
    int rl = row < N ? row : N - 1;
    #pragma unroll
    for (int kc = 0; kc < 4; ++kc) {
      const float* ap = A + (size_t)rl*128 + kc*32 + quad*8;
      cur[2*kc]   = *(const float4*)(ap);
      cur[2*kc+1] = *(const float4*)(ap + 4);
    }
  }
  while (tile < ntiles) {
    int tnext = tile + gridDim.x;
    float4 nxt[8];
    if (tnext < ntiles) {            // wave-uniform branch
      int row = tnext * 64 + wave * 16 + j;
      int rl = row < N ? row : N - 1;
      #pragma unroll
      for (int kc = 0; kc < 4; ++kc) {
        const float* ap = A + (size_t)rl*128 + kc*32 + quad*8;
        nxt[2*kc]   = *(const float4*)(ap);
        nxt[2*kc+1] = *(const float4*)(ap + 4);
      }
    }
    floatx4 acc[8];
    #pragma unroll
    for (int ct = 0; ct < 8; ++ct) acc[ct] = (floatx4){0.f,0.f,0.f,0.f};
    #pragma unroll
    for (int kc = 0; kc < 4; ++kc) {
      float4 f0 = cur[2*kc], f1 = cur[2*kc+1];
      uint4 H, L;
      hilo2(f0.x, f0.y, H.x, L.x);
      hilo2(f0.z, f0.w, H.y, L.y);
      hilo2(f1.x, f1.y, H.z, L.z);
      hilo2(f1.z, f1.w, H.w, L.w);
      bf16x8 ah = asbf(H), al = asbf(L);
      #pragma unroll
      for (int ct = 0; ct < 8; ++ct) {
        int nr = ct*16 + j;
        uint4 bh = Bhi[nr*16 + kc*4 + quad];
        uint4 bl = Blo[nr*16 + kc*4 + quad];
        acc[ct] = __builtin_amdgcn_mfma_f32_16x16x32_bf16(ah, asbf(bh), acc[ct], 0, 0, 0);
        acc[ct] = __builtin_amdgcn_mfma_f32_16x16x32_bf16(ah, asbf(bl), acc[ct], 0, 0, 0);
        acc[ct] = __builtin_amdgcn_mfma_f32_16x16x32_bf16(al, asbf(bh), acc[ct], 0, 0, 0);
      }
    }
    int row0 = tile * 64 + wave * 16;
    #pragma unroll
    for (int ct = 0; ct < 8; ++ct) {
      int colc = ct*16 + j;
      float bs = bias[colc];
      #pragma unroll
      for (int r = 0; r < 4; ++r) {
        int grow = row0 + quad*4 + r;
        if (grow < N) {
          float v = acc[ct][r] + bs;
          Out[(size_t)grow*128 + colc] = v;
          st[ct] += v;
          sst[ct] += v*v;
        }
      }
    }
    #pragma unroll
    for (int i = 0; i < 8; ++i) cur[i] = nxt[i];
    tile = tnext;
  }
  // cross-quad reduce (lanes j, j+16, j+32, j+48 hold the same column)
  #pragma unroll
  for (int ct = 0; ct < 8; ++ct) {
    float s = st[ct], ss = sst[ct];
    s  += __shfl_xor(s, 16);  s  += __shfl_xor(s, 32);
    ss += __shfl_xor(ss, 16); ss += __shfl_xor(ss, 32);
    if (quad == 0) { sblk[wave][ct*16+j] = s; ssblk[wave][ct*16+j] = ss; }
  }
  __syncthreads();
  int tid = threadIdx.x;
  if (tid < 128) {
    float s  = sblk[0][tid] + sblk[1][tid] + sblk[2][tid] + sblk[3][tid];
    float ss = ssblk[0][tid] + ssblk[1][tid] + ssblk[2][tid] + ssblk[3][tid];
    Ps [(size_t)blockIdx.x*128 + tid] = s;
    Pss[(size_t)blockIdx.x*128 + tid] = ss;
  }
}

// reduce per-block partials -> colA/colB (1 block, 128 threads, 4-way unrolled)
__global__ void bn_finalize_kernel(const float* __restrict__ Ps, const float* __restrict__ Pss,
                                   const float* __restrict__ g, const float* __restrict__ be,
                                   float* __restrict__ colA, float* __restrict__ colB,
                                   int nt, float invN) {
  int f = threadIdx.x;
  float s0 = 0.f, s1 = 0.f, s2 = 0.f, s3 = 0.f;
  float q0 = 0.f, q1 = 0.f, q2 = 0.f, q3 = 0.f;
  int t = 0;
  for (; t + 4 <= nt; t += 4) {
    s0 += Ps[(size_t)(t+0)*128 + f];
    s1 += Ps[(size_t)(t+1)*128 + f];
    s2 += Ps[(size_t)(t+2)*128 + f];
    s3 += Ps[(size_t)(t+3)*128 + f];
    q0 += Pss[(size_t)(t+0)*128 + f];
    q1 += Pss[(size_t)(t+1)*128 + f];
    q2 += Pss[(size_t)(t+2)*128 + f];
    q3 += Pss[(size_t)(t+3)*128 + f];
  }
  for (; t < nt; ++t) { s0 += Ps[(size_t)t*128 + f]; q0 += Pss[(size_t)t*128 + f]; }
  float s = (s0 + s1) + (s2 + s3);
  float ss = (q0 + q1) + (q2 + q3);
  float mu  = s * invN;
  float var = ss * invN - mu*mu;
  if (var < 0.f) var = 0.f;
  float rs = rsqrtf(var + 1e-5f);
  float a = g[f] * rs;
  colA[f] = a;
  colB[f] = be[f] - mu*a;
}

// ---------------- FUSED: BN-apply + ReLU + MFMA GEMM (128 -> 40, bf16 out) ----------------
__global__ __launch_bounds__(256) void bn_gemm40_kernel(
    const float* __restrict__ A,
    const float* __restrict__ colA, const float* __restrict__ colB,
    const uint4* __restrict__ Bhi, const uint4* __restrict__ Blo,
    const float* __restrict__ rowscale,
    unsigned short* __restrict__ OutB, int N) {
  int wave = threadIdx.x >> 6;
  int lane = threadIdx.x & 63;
  int quad = lane >> 4, j = lane & 15;
  int row0 = blockIdx.x * 64 + wave * 16;
  int row = row0 + j;
  int rl = row < N ? row : N - 1;
  floatx4 acc[3];
  #pragma unroll
  for (int ct = 0; ct < 3; ++ct) acc[ct] = (floatx4){0.f,0.f,0.f,0.f};
  #pragma unroll
  for (int kc = 0; kc < 4; ++kc) {
    const float* ap = A + (size_t)rl*128 + kc*32 + quad*8;
    float4 f0 = *(const float4*)(ap);
    float4 f1 = *(const float4*)(ap + 4);
    const float* ca = colA + kc*32 + quad*8;
    const float* cb = colB + kc*32 + quad*8;
    float4 a0 = *(const float4*)(ca), a1 = *(const float4*)(ca + 4);
    float4 b0 = *(const float4*)(cb), b1 = *(const float4*)(cb + 4);
    float y0 = fmaxf(f0.x*a0.x + b0.x, 0.f);
    float y1 = fmaxf(f0.y*a0.y + b0.y, 0.f);
    float y2 = fmaxf(f0.z*a0.z + b0.z, 0.f);
    float y3 = fmaxf(f0.w*a0.w + b0.w, 0.f);
    float y4 = fmaxf(f1.x*a1.x + b1.x, 0.f);
    float y5 = fmaxf(f1.y*a1.y + b1.y, 0.f);
    float y6 = fmaxf(f1.z*a1.z + b1.z, 0.f);
    float y7 = fmaxf(f1.w*a1.w + b1.w, 0.f);
    uint4 H, L;
    hilo2(y0, y1, H.x, L.x);
    hilo2(y2, y3, H.y, L.y);
    hilo2(y4, y5, H.z, L.z);
    hilo2(y6, y7, H.w, L.w);
    bf16x8 ah = asbf(H), al = asbf(L);
    #pragma unroll
    for (int ct = 0; ct < 3; ++ct) {
      int nr = ct*16 + j;
      uint4 bh = Bhi[nr*16 + kc*4 + quad];
      uint4 bl = Blo[nr*16 + kc*4 + quad];
      acc[ct] = __builtin_amdgcn_mfma_f32_16x16x32_bf16(ah, asbf(bh), acc[ct], 0, 0, 0);
      acc[ct] = __builtin_amdgcn_mfma_f32_16x16x32_bf16(ah, asbf(bl), acc[ct], 0, 0, 0);
      acc[ct] = __builtin_amdgcn_mfma_f32_16x16x32_bf16(al, asbf(bh), acc[ct], 0, 0, 0);
    }
  }
  #pragma unroll
  for (int r = 0; r < 4; ++r) {
    int grow = row0 + quad*4 + r;
    if (grow < N) {
      float sc = rowscale[grow];
      #pragma unroll
      for (int ct = 0; ct < 3; ++ct) {
        int colc = ct*16 + j;
        if (colc < 40) OutB[(size_t)grow*40 + colc] = f2bf(acc[ct][r] * sc);
      }
    }
  }
}

// bf16 out, pre-scaled by dout_is (feeds the layer-2 gather)
__global__ void bn_apply_bf16_kernel(const float* __restrict__ raw, const float* __restrict__ colA,
                                     const float* __restrict__ colB, const float* __restrict__ dout_is,
                                     unsigned* __restrict__ outb, int n4) {
  int i = blockIdx.x * blockDim.x + threadIdx.x;
  if (i >= n4) return;
  float4 v = ((const float4*)raw)[i];
  int c4 = i & 31;
  int row = i >> 5;
  float sc = dout_is[row];
  float4 a = ((const float4*)colA)[c4];
  float4 b = ((const float4*)colB)[c4];
  float x0 = fmaxf(v.x*a.x + b.x, 0.f) * sc;
  float x1 = fmaxf(v.y*a.y + b.y, 0.f) * sc;
  float x2 = fmaxf(v.z*a.z + b.z, 0.f) * sc;
  float x3 = fmaxf(v.w*a.w + b.w, 0.f) * sc;
  unsigned lo = (unsigned)f2bf(x0) | ((unsigned)f2bf(x1) << 16);
  unsigned hi = (unsigned)f2bf(x2) | ((unsigned)f2bf(x3) << 16);
  ((uint2*)outb)[i] = make_uint2(lo, hi);
}

// ---------------- layer 3: aggregate 40-dim bf16 (pre-scaled) + bias + log_softmax ----------------
__global__ __launch_bounds__(256) void final_kernel(
    const unsigned* __restrict__ tb,
    const int* __restrict__ rp, const int* __restrict__ col,
    const float* __restrict__ din_is, const float* __restrict__ b3,
    float* __restrict__ out, int N) {
  int wave = (blockIdx.x * blockDim.x + threadIdx.x) >> 6;
  int g = (threadIdx.x >> 5) & 1;
  int j = threadIdx.x & 31;
  int d = wave * 2 + g;
  if (d >= N) return;
  bool act = (j < 20);
  int s0 = rp[d], s1 = rp[d+1];
  float a0 = 0.f, a1 = 0.f;
  int e = s0;
  for (; e + 8 <= s1; e += 8) {
    int c0 = col[e],   c1 = col[e+1], c2 = col[e+2], c3 = col[e+3];
    int c4 = col[e+4], c5 = col[e+5], c6 = col[e+6], c7 = col[e+7];
    unsigned u0 = act ? tb[(size_t)c0*20 + j] : 0u;
    unsigned u1 = act ? tb[(size_t)c1*20 + j] : 0u;
    unsigned u2 = act ? tb[(size_t)c2*20 + j] : 0u;
    unsigned u3 = act ? tb[(size_t)c3*20 + j] : 0u;
    unsigned u4 = act ? tb[(size_t)c4*20 + j] : 0u;
    unsigned u5 = act ? tb[(size_t)c5*20 + j] : 0u;
    unsigned u6 = act ? tb[(size_t)c6*20 + j] : 0u;
    unsigned u7 = act ? tb[(size_t)c7*20 + j] : 0u;
    float2 f0 = bfp2f2(u0), f1 = bfp2f2(u1), f2 = bfp2f2(u2), f3 = bfp2f2(u3);
    float2 f4 = bfp2f2(u4), f5 = bfp2f2(u5), f6 = bfp2f2(u6), f7 = bfp2f2(u7);
    a0 += ((f0.x + f1.x) + (f2.x + f3.x)) + ((f4.x + f5.x) + (f6.x + f7.x));
    a1 += ((f0.y + f1.y) + (f2.y + f3.y)) + ((f4.y + f5.y) + (f6.y + f7.y));
  }
  for (; e + 4 <= s1; e += 4) {
    int c0 = col[e], c1 = col[e+1], c2 = col[e+2], c3 = col[e+3];
    unsigned u0 = act ? tb[(size_t)c0*20 + j] : 0u;
    unsigned u1 = act ? tb[(size_t)c1*20 + j] : 0u;
    unsigned u2 = act ? tb[(size_t)c2*20 + j] : 0u;
    unsigned u3 = act ? tb[(size_t)c3*20 + j] : 0u;
    float2 f0 = bfp2f2(u0), f1 = bfp2f2(u1), f2 = bfp2f2(u2), f3 = bfp2f2(u3);
    a0 += (f0.x + f1.x) + (f2.x + f3.x);
    a1 += (f0.y + f1.y) + (f2.y + f3.y);
  }
  for (; e < s1; ++e) {
    unsigned u = act ? tb[(size_t)col[e]*20 + j] : 0u;
    float2 f = bfp2f2(u);
    a0 += f.x; a1 += f.y;
  }
  float di = din_is[d];
  float z0 = act ? di*a0 + b3[2*j]   : -1e30f;
  float z1 = act ? di*a1 + b3[2*j+1] : -1e30f;
  float m = fmaxf(z0, z1);
  #pragma unroll
  for (int off=16; off>0; off>>=1) m = fmaxf(m, __shfl_xor(m, off, 32));
  float s = act ? (expf(z0-m) + expf(z1-m)) : 0.f;
  #pragma unroll
  for (int off=16; off>0; off>>=1) s += __shfl_xor(s, off, 32);
  float lg = logf(s);
  if (act) {
    float2 o = make_float2(z0 - m - lg, z1 - m - lg);
    ((float2*)(out + (size_t)d*40))[j] = o;
  }
}

// ---------------- host ----------------
extern "C" void kernel_launch(void* const* d_in, const int* in_sizes, int n_in,
                              void* d_out, int out_size, void* d_ws, size_t ws_size,
                              hipStream_t stream) {
  const float* x   = (const float*)d_in[0];
  const int*   src = (const int*)d_in[1];
  const int*   dst = (const int*)d_in[2];
  const float* W1  = (const float*)d_in[3];
  const float* b1  = (const float*)d_in[4];
  const float* g1  = (const float*)d_in[5];
  const float* be1 = (const float*)d_in[6];
  const float* W2  = (const float*)d_in[7];
  const float* b2  = (const float*)d_in[8];
  const float* g2  = (const float*)d_in[9];
  const float* be2 = (const float*)d_in[10];
  const float* W3  = (const float*)d_in[11];
  const float* b3  = (const float*)d_in[12];
  const int E = in_sizes[1];
  const int D = in_sizes[4];     // 128
  const int N = in_sizes[0] / D; // 100000
  float* out = (float*)d_out;

  char* p = (char*)d_ws;
  auto alloc = [&](size_t bytes) { char* q = p; p += (bytes + 255) & ~(size_t)255; return q; };
  int* rp        = (int*)alloc((size_t)(N+1)*4);
  float* din_is  = (float*)alloc((size_t)N*4);
  float* dout_is = (float*)alloc((size_t)N*4);
  float* colAp   = (float*)alloc((size_t)D*4);
  float* colBp   = (float*)alloc((size_t)D*4);
  int* bcnt      = (int*)alloc((size_t)MAXNB*4);
  int* bbase     = (int*)alloc((size_t)(MAXNB+1)*4);
  int* bcur      = (int*)alloc((size_t)MAXNB*4);
  int* scnt      = (int*)alloc((size_t)MAXNB*4);
  int* sbase     = (int*)alloc((size_t)(MAXNB+1)*4);
  int* scur      = (int*)alloc((size_t)MAXNB*4);
  unsigned short* Wt1hi = (unsigned short*)alloc(128*128*2);
  unsigned short* Wt1lo = (unsigned short*)alloc(128*128*2);
  unsigned short* Wt2hi = (unsigned short*)alloc(128*128*2);
  unsigned short* Wt2lo = (unsigned short*)alloc(128*128*2);
  unsigned short* Wt3hi = (unsigned short*)alloc(48*128*2);
  unsigned short* Wt3lo = (unsigned short*)alloc(48*128*2);
  int*   col     = (int*)alloc((size_t)E*4);
  float* bufA    = (float*)alloc((size_t)N*D*4);      // GEMM output (fp32)
  float* bufB    = (float*)alloc((size_t)N*D*4);      // agg output (fp32)
  unsigned* bf16buf = (unsigned*)alloc((size_t)N*D*2);
  // aliases: CSR build finishes before bufA/bufB first writes
  unsigned* ebuf = (unsigned*)bufA;   // E uints (packed dst-low|src)
  unsigned* sbuf = (unsigned*)bufB;   // E uints (src)

  const int NB = (N + 255) >> 8;
  int cntB = (E + BCH_CNT - 1)/BCH_CNT;
  int binB = (E + BCH_BIN - 1)/BCH_BIN;

  int ntiles = (N + 63)/64;               // 1563
  int gemb2  = (ntiles + 1)/2;            // 782 blocks, 2 tiles each
  float* Ps  = (float*)alloc((size_t)gemb2*128*4);
  float* Pss = (float*)alloc((size_t)gemb2*128*4);

  hipMemsetAsync(bcnt, 0, (size_t)MAXNB*4, stream);
  hipMemsetAsync(scnt, 0, (size_t)MAXNB*4, stream);
  wt_hilo_kernel<<<(128*128+255)/256, 256, 0, stream>>>(W1, Wt1hi, Wt1lo, 128, 128);
  wt_hilo_kernel<<<(128*128+255)/256, 256, 0, stream>>>(W2, Wt2hi, Wt2lo, 128, 128);
  wt_hilo_kernel<<<(48*128+255)/256, 256, 0, stream>>>(W3, Wt3hi, Wt3lo, 40, 48);
  count2_kernel<<<cntB, 256, 0, stream>>>(src, dst, bcnt, scnt, E, NB);
  scan2_kernel<<<1, 256, 0, stream>>>(bcnt, bbase, bcur, scnt, sbase, scur, rp, NB, N, E);
  bin_dst_kernel<<<binB, 256, 0, stream>>>(src, dst, bcur, ebuf, E, NB);
  bin_src_kernel<<<binB, 256, 0, stream>>>(src, scur, sbuf, E, NB);
  finalize_dst_kernel<<<NB, 256, 0, stream>>>(ebuf, bbase, rp, din_is, col, N);
  finalize_src_kernel<<<NB, 256, 0, stream>>>(sbuf, sbase, dout_is, N);

  int aggb = ((N + 3)/4*64 + 255)/256;    // 4 dst per wave
  int finb = ((N + 1)/2*64 + 255)/256;    // 2 dst per wave
  int gemb = (N + 63)/64;                 // 64 rows per block (bn_gemm40)
  int nel4 = (N*D)/4;

  // layer 1
  cast_scale_kernel<<<(nel4+255)/256, 256, 0, stream>>>(x, dout_is, bf16buf, nel4);
  agg128_kernel<<<aggb, 256, 0, stream>>>((const uint4*)bf16buf, rp, col, din_is, bufB, N);
  gemm128_stats_kernel<<<gemb2, 256, 0, stream>>>(bufB, (const uint4*)Wt1hi, (const uint4*)Wt1lo,
                                                  b1, bufA, Ps, Pss, N, ntiles);
  bn_finalize_kernel<<<1, 128, 0, stream>>>(Ps, Pss, g1, be1, colAp, colBp, gemb2, 1.0f/(float)N);
  bn_apply_bf16_kernel<<<(nel4+255)/256, 256, 0, stream>>>(bufA, colAp, colBp, dout_is, bf16buf, nel4);

  // layer 2
  agg128_kernel<<<aggb, 256, 0, stream>>>((const uint4*)bf16buf, rp, col, din_is, bufB, N);
  gemm128_stats_kernel<<<gemb2, 256, 0, stream>>>(bufB, (const uint4*)Wt2hi, (const uint4*)Wt2lo,
                                                  b2, bufA, Ps, Pss, N, ntiles);
  bn_finalize_kernel<<<1, 128, 0, stream>>>(Ps, Pss, g2, be2, colAp, colBp, gemb2, 1.0f/(float)N);

  // layer 3: fused BN + GEMM to 40 dims (bf16 out pre-scaled by dout), then agg + softmax
  bn_gemm40_kernel<<<gemb, 256, 0, stream>>>(bufA, colAp, colBp,
                                             (const uint4*)Wt3hi, (const uint4*)Wt3lo,
                                             dout_is, (unsigned short*)bf16buf, N);
  final_kernel<<<finb, 256, 0, stream>>>((const unsigned*)bf16buf, rp, col, din_is, b3, out, N);
}